// Round 4
// baseline (299.474 us; speedup 1.0000x reference)
//
#include <hip/hip_runtime.h>
#include <hip/hip_bf16.h>

// BiMPM matching, B=32, L=128, H=200, NP=20.
// Input/output dtype (bf16 vs f32) detected at runtime from mask_p[0] bit
// pattern. All compute in f32 via ws; maxpool GEMM uses bf16 MFMA (error
// bound |dcos| <= 2^-9, under the 1.57e-2 threshold).
// Output: mv_p (32,128,105), mv_h same.

#define EPSF 1e-8f
#define NEGF -1e7f

constexpr int Bc = 32, Lc = 128, Hc = 200, NPc = 20, NCHc = 105;
constexpr int KP = 224;    // maxpool padded K (7 x 32)
constexpr int LDK = 232;   // LDS row stride in shorts (bank-friendly: 116 dw = 20 mod 32)
constexpr size_t SLH = (size_t)Bc * Lc * Hc;   // 819200
constexpr size_t SLL = (size_t)Bc * Lc * Lc;   // 524288

// workspace layout (floats)
constexpr size_t OFF_CPM    = 0;
constexpr size_t OFF_CHM    = OFF_CPM + SLH;
constexpr size_t OFF_CHMT   = OFF_CHM + SLH;       // [b][h][l]
constexpr size_t OFF_COS    = OFF_CHMT + SLH;      // [b][p][q]
constexpr size_t OFF_COST   = OFF_COS + SLL;       // [b][q][p]
constexpr size_t OFF_AMEANH = OFF_COST + SLL;      // (b,Lp,H)
constexpr size_t OFF_AMAXH  = OFF_AMEANH + SLH;
constexpr size_t OFF_AMEANP = OFF_AMAXH + SLH;     // (b,Lh,H)
constexpr size_t OFF_AMAXP  = OFF_AMEANP + SLH;
constexpr size_t OFF_NORMP  = OFF_AMAXP + SLH;
constexpr size_t OFF_NORMH  = OFF_NORMP + (size_t)Bc * Lc;
constexpr size_t OFF_ROWSUM = OFF_NORMH + (size_t)Bc * Lc;
constexpr size_t OFF_COLSUM = OFF_ROWSUM + (size_t)Bc * Lc;
constexpr size_t OFF_LENP   = OFF_COLSUM + (size_t)Bc * Lc;
constexpr size_t OFF_LENH   = OFF_LENP + Bc;
constexpr size_t OFF_LASTP  = OFF_LENH + Bc;
constexpr size_t OFF_LASTH  = OFF_LASTP + (size_t)Bc * Hc;
constexpr size_t OFF_NWP    = OFF_LASTH + (size_t)Bc * Hc;  // [b][np][l]
constexpr size_t OFF_NWH    = OFF_NWP + (size_t)Bc * NPc * Lc;
constexpr size_t OFF_MASKPF = OFF_NWH + (size_t)Bc * NPc * Lc;
constexpr size_t OFF_MASKHF = OFF_MASKPF + (size_t)Bc * Lc;
constexpr size_t OFF_WFULL  = OFF_MASKHF + (size_t)Bc * Lc;
constexpr size_t OFF_WMP    = OFF_WFULL + (size_t)NPc * Hc;
constexpr size_t OFF_WATT   = OFF_WMP + (size_t)NPc * Hc;
constexpr size_t OFF_WMATT  = OFF_WATT + (size_t)NPc * Hc;
constexpr size_t OFF_FLAG   = OFF_WMATT + (size_t)NPc * Hc;
constexpr size_t OFF_WT     = OFF_FLAG + 64;                // [h][64] squared-weights table
constexpr size_t OFF_RPMAX  = OFF_WT + (size_t)Hc * 64;     // [qi][b][np][p]
constexpr size_t OFF_RPSUM  = OFF_RPMAX + 2 * (size_t)Bc * NPc * Lc;
constexpr size_t OFF_CPMAX  = OFF_RPSUM + 2 * (size_t)Bc * NPc * Lc;  // [pi][b][np][q]
constexpr size_t OFF_CPSUM  = OFF_CPMAX + 2 * (size_t)Bc * NPc * Lc;
constexpr size_t OFF_CHB    = OFF_CPSUM + 2 * (size_t)Bc * NPc * Lc;  // bf16 [b][l][KP]
constexpr size_t WS_FLOATS  = OFF_CHB + ((size_t)Bc * Lc * KP) / 2;   // ~8.13M floats (~32.5 MB)

typedef __attribute__((ext_vector_type(8))) short short8v;
typedef __attribute__((ext_vector_type(4))) short short4v;
typedef __attribute__((ext_vector_type(4))) float float4v;

__device__ __forceinline__ float loadf(const void* p, size_t i, int isb) {
  if (isb) return __bfloat162float(((const __hip_bfloat16*)p)[i]);
  return ((const float*)p)[i];
}

__device__ __forceinline__ void storef(void* out, size_t i, float v, int isb) {
  if (isb) ((__hip_bfloat16*)out)[i] = __float2bfloat16(v);
  else ((float*)out)[i] = v;
}

__device__ __forceinline__ short b2s(float f) {
  __hip_bfloat16 h = __float2bfloat16(f);
  union { __hip_bfloat16 b; short s; } u;
  u.b = h;
  return u.s;
}

// ---------------- dtype detect + convert small inputs + wT table -------------
__global__ void convert_kernel(const void* mp, const void* mh, const void* wf,
                               const void* wmp, const void* watt, const void* wma,
                               float* __restrict__ ws) {
  int isb = (((const unsigned short*)mp)[0] == 0x3F80u) ? 1 : 0;
  int g = blockIdx.x * 256 + threadIdx.x;
  if (g == 0) ws[OFF_FLAG] = (float)isb;
  const int n0 = Bc * Lc;          // 4096
  const int nw = NPc * Hc;         // 4000
  if (g < n0) {
    ws[OFF_MASKPF + g] = loadf(mp, g, isb);
  } else if (g < 2 * n0) {
    ws[OFF_MASKHF + (g - n0)] = loadf(mh, g - n0, isb);
  } else if (g < 2 * n0 + 4 * nw) {
    int r = g - 2 * n0;
    int seg = r / nw, off = r % nw;
    if (seg == 0) ws[OFF_WFULL + off] = loadf(wf, off, isb);
    else if (seg == 1) ws[OFF_WMP + off] = loadf(wmp, off, isb);
    else if (seg == 2) ws[OFF_WATT + off] = loadf(watt, off, isb);
    else ws[OFF_WMATT + off] = loadf(wma, off, isb);
  } else if (g < 2 * n0 + 4 * nw + Hc * 64) {
    int r = g - (2 * n0 + 4 * nw);
    int h = r >> 6, c = r & 63;
    float w = 1.0f;
    if (c < 20) w = loadf(wf, (size_t)c * Hc + h, isb);
    else if (c < 40) w = loadf(watt, (size_t)(c - 20) * Hc + h, isb);
    else if (c < 60) w = loadf(wma, (size_t)(c - 40) * Hc + h, isb);
    ws[OFF_WT + r] = w * w;
  }
}

// ---------------- prep: masked copies, chmT, chb(bf16), norms, w-norms -------
__global__ void prep_kernel(const void* __restrict__ ctx_p,
                            const void* __restrict__ ctx_h,
                            float* __restrict__ ws) {
  int bid = blockIdx.x;
  int side = bid >> 12;
  int bl = bid & 4095;
  int b = bl >> 7, l = bl & 127;
  int lane = threadIdx.x;      // 64
  int isb = ws[OFF_FLAG] > 0.5f;
  const void* ctx = side ? ctx_h : ctx_p;
  const float* mask = ws + (side ? OFF_MASKHF : OFF_MASKPF);
  float mk = mask[b * Lc + l];
  size_t rowbase = ((size_t)b * Lc + l) * Hc;
  float* cm = ws + (side ? OFF_CHM : OFF_CPM) + rowbase;
  __hip_bfloat16* chb = (__hip_bfloat16*)(ws + OFF_CHB);
  size_t cb = ((size_t)b * Lc + l) * KP;

  float v[4];
  float ss = 0.f;
  for (int i = 0; i < 4; i++) {
    int h = lane + 64 * i;
    float x = 0.f;
    if (h < Hc) {
      x = loadf(ctx, rowbase + h, isb) * mk;
      cm[h] = x;
      if (side) {
        ws[OFF_CHMT + ((size_t)b * Hc + h) * Lc + l] = x;
        chb[cb + h] = __float2bfloat16(x);
      }
    } else if (side && h < KP) {
      chb[cb + h] = __float2bfloat16(0.f);
    }
    v[i] = x;
    ss += x * x;
  }
  for (int o = 32; o > 0; o >>= 1) ss += __shfl_xor(ss, o);
  if (lane == 0) ws[(side ? OFF_NORMH : OFF_NORMP) + b * Lc + l] = sqrtf(ss);

  const float* wmpf = ws + OFF_WMP;
  float* nw = ws + (side ? OFF_NWH : OFF_NWP) + (size_t)b * NPc * Lc;
  for (int np_ = 0; np_ < NPc; np_++) {
    float s = 0.f;
    for (int i = 0; i < 4; i++) {
      int h = lane + 64 * i;
      if (h < Hc) {
        float w = wmpf[np_ * Hc + h];
        float wx = w * v[i];
        s += wx * wx;
      }
    }
    for (int o = 32; o > 0; o >>= 1) s += __shfl_xor(s, o);
    if (lane == 0) nw[np_ * Lc + l] = sqrtf(s);
  }
}

// ---------------- lengths + last-token vectors -------------------------------
__global__ void lastlen_kernel(const void* __restrict__ ctx_p,
                               const void* __restrict__ ctx_h,
                               float* __restrict__ ws) {
  int side = blockIdx.x >> 5, b = blockIdx.x & 31;
  int lane = threadIdx.x;  // 64
  int isb = ws[OFF_FLAG] > 0.5f;
  const float* mask = ws + (side ? OFF_MASKHF : OFF_MASKPF);
  const void* ctx = side ? ctx_h : ctx_p;
  float s = 0.f;
  for (int l = lane; l < Lc; l += 64) s += mask[b * Lc + l];
  for (int o = 32; o > 0; o >>= 1) s += __shfl_xor(s, o);
  if (lane == 0) ws[(side ? OFF_LENH : OFF_LENP) + b] = s;
  int idx = (int)(s + 0.5f) - 1;
  if (idx < 0) idx = 0;
  float mk = mask[b * Lc + idx];
  float* lastv = ws + (side ? OFF_LASTH : OFF_LASTP) + (size_t)b * Hc;
  for (int h = lane; h < Hc; h += 64)
    lastv[h] = loadf(ctx, ((size_t)b * Lc + idx) * Hc + h, isb) * mk;
}

// ---------------- cos matrix (and transpose) ---------------------------------
__global__ void cos_kernel(float* __restrict__ ws) {
  int b = blockIdx.x >> 7, p = blockIdx.x & 127;
  int t = threadIdx.x;  // 128
  __shared__ float v1s[Hc];
  for (int h = t; h < Hc; h += 128) v1s[h] = ws[OFF_CPM + ((size_t)b * Lc + p) * Hc + h];
  __syncthreads();
  const float* bT = ws + OFF_CHMT + (size_t)b * Hc * Lc;
  float acc = 0.f;
#pragma unroll 8
  for (int h = 0; h < Hc; h++) acc += v1s[h] * bT[(size_t)h * Lc + t];
  float denom = fmaxf(ws[OFF_NORMP + b * Lc + p] * ws[OFF_NORMH + b * Lc + t], EPSF);
  float cv = acc / denom;
  ws[OFF_COS + ((size_t)b * Lc + p) * Lc + t] = cv;
  ws[OFF_COST + ((size_t)b * Lc + t) * Lc + p] = cv;
}

// ---------------- cos row reductions: channels 0,1 + row/col sums ------------
__global__ void cosred_kernel(const float* __restrict__ rows,
                              const float* __restrict__ maskLoop,
                              const float* __restrict__ maskRow,
                              const float* __restrict__ lenOther,
                              float* __restrict__ sumdst,
                              void* __restrict__ outbase, size_t obase,
                              const float* __restrict__ wsflag) {
  int b = blockIdx.x >> 7, r = blockIdx.x & 127;
  int t = threadIdx.x;  // 128
  int isb = wsflag[0] > 0.5f;
  float c = rows[((size_t)b * Lc + r) * Lc + t];
  float ml = maskLoop[b * Lc + t];
  float mval = (ml > 0.f) ? c : NEGF;
  float sval = c;
  for (int o = 32; o > 0; o >>= 1) {
    mval = fmaxf(mval, __shfl_xor(mval, o));
    sval += __shfl_xor(sval, o);
  }
  __shared__ float sm[2], ssm[2];
  if ((t & 63) == 0) { sm[t >> 6] = mval; ssm[t >> 6] = sval; }
  __syncthreads();
  if (t == 0) {
    float m = fmaxf(sm[0], sm[1]);
    float s = ssm[0] + ssm[1];
    sumdst[b * Lc + r] = s;
    float mr = maskRow[b * Lc + r];
    size_t orow = obase + ((size_t)b * Lc + r) * NCHc;
    storef(outbase, orow + 0, mr * m, isb);
    storef(outbase, orow + 1, mr * s / fmaxf(mr * lenOther[b], EPSF), isb);
  }
}

// ---------------- fused attentive mean + max ---------------------------------
__global__ void att_kernel(const float* __restrict__ cosrows,
                           const float* __restrict__ vsrc,
                           const float* __restrict__ denom,
                           const float* __restrict__ maskLoop,
                           const float* __restrict__ maskRow,
                           float* __restrict__ amean, float* __restrict__ amax) {
  int b = blockIdx.x >> 7, r = blockIdx.x & 127;
  int t = threadIdx.x;  // 256
  __shared__ float crow[Lc];
  __shared__ float mrow[Lc];
  if (t < Lc) {
    crow[t] = cosrows[((size_t)b * Lc + r) * Lc + t];
    mrow[t] = maskLoop[b * Lc + t];
  }
  __syncthreads();
  if (t < Hc) {
    float s = 0.f, m = NEGF;
    const float* vb = vsrc + (size_t)b * Lc * Hc + t;
#pragma unroll 4
    for (int q = 0; q < Lc; q++) {
      float pr = crow[q] * vb[(size_t)q * Hc];
      s += pr;
      if (mrow[q] > 0.f) m = fmaxf(m, pr);
    }
    float den = fmaxf(denom[b * Lc + r], EPSF);
    amean[((size_t)b * Lc + r) * Hc + t] = s / den;
    amax[((size_t)b * Lc + r) * Hc + t] = maskRow[b * Lc + r] * m;
  }
}

// ---------------- maxpool: 64x64x224 bf16-MFMA per (quadrant,np,b) wave ------
__global__ __launch_bounds__(64) void maxpool_kernel(float* __restrict__ ws) {
  int s = blockIdx.x;            // 0..3
  int np_ = blockIdx.y, b = blockIdx.z;
  int pi = s >> 1, qi = s & 1;
  int lane = threadIdx.x;        // 64, single wave
  __shared__ short Ash[64][LDK];
  __shared__ short Bsh[64][LDK];
  __shared__ float w2s[Hc];

  // squared per-perspective weights
  for (int h = lane; h < Hc; h += 64) {
    float w = ws[OFF_WMP + np_ * Hc + h];
    w2s[h] = w * w;
  }
  // B stage: raw bf16 chb rows (K pre-padded with zeros to KP)
  {
    const short* src = (const short*)(ws + OFF_CHB) + ((size_t)b * Lc + qi * 64) * KP;
#pragma unroll
    for (int i = 0; i < 28; i++) {
      int flat = i * 64 + lane;       // 0..1791 = 64 rows x 28 chunks
      int r = flat / 28, c = flat % 28;
      *(short8v*)&Bsh[r][c * 8] = *(const short8v*)(src + (size_t)r * KP + c * 8);
    }
  }
  // zero A pad columns [200,224)
  {
    short4v z = {0, 0, 0, 0};
#pragma unroll
    for (int j = 0; j < 6; j++) *(short4v*)&Ash[lane][Hc + j * 4] = z;
  }
  __syncthreads();
  // A stage: bf16(w^2 * cp)
  {
    const float* cp = ws + OFF_CPM + ((size_t)b * Lc + pi * 64) * Hc;
#pragma unroll 2
    for (int i = 0; i < 50; i++) {
      int flat = i * 64 + lane;       // 0..3199 = 64 rows x 50 quads
      int r = flat / 50, h4 = flat % 50;
      float4 x = *(const float4*)(cp + (size_t)r * Hc + h4 * 4);
      float4v wq = *(const float4v*)&w2s[h4 * 4];
      short4v o;
      o.x = b2s(x.x * wq[0]);
      o.y = b2s(x.y * wq[1]);
      o.z = b2s(x.z * wq[2]);
      o.w = b2s(x.w * wq[3]);
      *(short4v*)&Ash[r][h4 * 4] = o;
    }
  }
  __syncthreads();

  // MFMA sweep: 4x4 tiles of 16x16, K = 7 steps of 32
  float4v acc[4][4];
  float4v zf = {0.f, 0.f, 0.f, 0.f};
#pragma unroll
  for (int i = 0; i < 4; i++)
#pragma unroll
    for (int j = 0; j < 4; j++) acc[i][j] = zf;
  int rsel = lane & 15, quad = lane >> 4;
#pragma unroll
  for (int st = 0; st < 7; st++) {
    int k0 = st * 32 + quad * 8;
    short8v af[4], bf[4];
#pragma unroll
    for (int t = 0; t < 4; t++) af[t] = *(const short8v*)&Ash[t * 16 + rsel][k0];
#pragma unroll
    for (int t = 0; t < 4; t++) bf[t] = *(const short8v*)&Bsh[t * 16 + rsel][k0];
#pragma unroll
    for (int i = 0; i < 4; i++)
#pragma unroll
      for (int j = 0; j < 4; j++)
        acc[i][j] = __builtin_amdgcn_mfma_f32_16x16x32_bf16(af[i], bf[j], acc[i][j], 0, 0, 0);
  }

  // epilogue: v = acc / max(nwp*nwh, eps); masked max/mean partials, both axes
  const float* nwp = ws + OFF_NWP + ((size_t)b * NPc + np_) * Lc + pi * 64;
  const float* nwh = ws + OFF_NWH + ((size_t)b * NPc + np_) * Lc + qi * 64;
  const float* maskP = ws + OFF_MASKPF + b * Lc + pi * 64;
  const float* maskH = ws + OFF_MASKHF + b * Lc + qi * 64;
  float nhv[4], mhv[4], cmax[4], csum[4];
#pragma unroll
  for (int tj = 0; tj < 4; tj++) {
    int q = tj * 16 + rsel;
    nhv[tj] = nwh[q];
    mhv[tj] = maskH[q];
    cmax[tj] = NEGF;
    csum[tj] = 0.f;
  }
  size_t rbase = (((size_t)qi * Bc + b) * NPc + np_) * Lc + pi * 64;
  size_t cbase = (((size_t)pi * Bc + b) * NPc + np_) * Lc + qi * 64;
#pragma unroll
  for (int ti = 0; ti < 4; ti++) {
#pragma unroll
    for (int r = 0; r < 4; r++) {
      int p = ti * 16 + quad * 4 + r;
      float npv = nwp[p], mpv = maskP[p];
      float rm = NEGF, rs = 0.f;
#pragma unroll
      for (int tj = 0; tj < 4; tj++) {
        float v = acc[ti][tj][r] * __builtin_amdgcn_rcpf(fmaxf(npv * nhv[tj], EPSF));
        if (mhv[tj] > 0.f) rm = fmaxf(rm, v);
        rs += v * mhv[tj];
        if (mpv > 0.f) cmax[tj] = fmaxf(cmax[tj], v);
        csum[tj] += v * mpv;
      }
      // reduce over q within row p: lanes differing in bits 0-3 (col)
#pragma unroll
      for (int o = 1; o <= 8; o <<= 1) {
        rm = fmaxf(rm, __shfl_xor(rm, o));
        rs += __shfl_xor(rs, o);
      }
      if (rsel == 0) {
        ws[OFF_RPMAX + rbase + p] = rm;
        ws[OFF_RPSUM + rbase + p] = rs;
      }
    }
  }
  // reduce cols over p: lanes differing in bits 4-5 (quad)
#pragma unroll
  for (int tj = 0; tj < 4; tj++) {
#pragma unroll
    for (int o = 16; o <= 32; o <<= 1) {
      cmax[tj] = fmaxf(cmax[tj], __shfl_xor(cmax[tj], o));
      csum[tj] += __shfl_xor(csum[tj], o);
    }
  }
  if (quad == 0) {
#pragma unroll
    for (int tj = 0; tj < 4; tj++) {
      int q = tj * 16 + rsel;
      ws[OFF_CPMAX + cbase + q] = cmax[tj];
      ws[OFF_CPSUM + cbase + q] = csum[tj];
    }
  }
}

// ---------------- maxpool finalize: combine 2 partials, write channels -------
__global__ void mpfin_kernel(float* __restrict__ ws, void* __restrict__ out) {
  int g = blockIdx.x * 256 + threadIdx.x;  // 2*32*20*128 = 163840
  if (g >= 2 * Bc * NPc * Lc) return;
  int isb = ws[OFF_FLAG] > 0.5f;
  int l = g & 127;
  int r = g >> 7;
  int np_ = r % NPc;
  int t2 = r / NPc;
  int b = t2 & 31;
  int side = t2 >> 5;
  size_t i0 = (((size_t)0 * Bc + b) * NPc + np_) * Lc + l;
  size_t i1 = (((size_t)1 * Bc + b) * NPc + np_) * Lc + l;
  float m, sum, mk, len;
  if (side == 0) {
    m = fmaxf(ws[OFF_RPMAX + i0], ws[OFF_RPMAX + i1]);
    sum = ws[OFF_RPSUM + i0] + ws[OFF_RPSUM + i1];
    mk = ws[OFF_MASKPF + b * Lc + l];
    len = ws[OFF_LENH + b];
  } else {
    m = fmaxf(ws[OFF_CPMAX + i0], ws[OFF_CPMAX + i1]);
    sum = ws[OFF_CPSUM + i0] + ws[OFF_CPSUM + i1];
    mk = ws[OFF_MASKHF + b * Lc + l];
    len = ws[OFF_LENP + b];
  }
  size_t orow = (size_t)side * Bc * Lc * NCHc + ((size_t)b * Lc + l) * NCHc;
  storef(out, orow + 23 + np_, mk * m, isb);
  storef(out, orow + 43 + np_, mk * sum / fmaxf(mk * len, EPSF), isb);
}

// ---------------- mpm epilogue: lane-per-channel, no cross-lane --------------
__global__ __launch_bounds__(64) void mpm_kernel(float* __restrict__ ws,
                                                 void* __restrict__ out) {
  int bid = blockIdx.x;
  int side = bid >> 12;
  int b = (bid >> 7) & 31, l = bid & 127;
  int c = threadIdx.x;  // 64: lane = channel
  int isb = ws[OFF_FLAG] > 0.5f;
  __shared__ float v1s[Hc];
  __shared__ float v2s[3][Hc];
  const float* v1 = ws + (side ? OFF_CHM : OFF_CPM) + ((size_t)b * Lc + l) * Hc;
  const float* v2f = ws + (side ? OFF_LASTP : OFF_LASTH) + (size_t)b * Hc;
  const float* v2a = ws + (side ? OFF_AMEANP : OFF_AMEANH) + ((size_t)b * Lc + l) * Hc;
  const float* v2m = ws + (side ? OFF_AMAXP : OFF_AMAXH) + ((size_t)b * Lc + l) * Hc;
  for (int h = c; h < Hc; h += 64) {
    v1s[h] = v1[h];
    v2s[0][h] = v2f[h];
    v2s[1][h] = v2a[h];
    v2s[2][h] = v2m[h];
  }
  __syncthreads();
  int v2i = (c < 20) ? 0 : (c < 40) ? 1 : (c < 60) ? 2 : (c - 60);
  if (v2i > 2) v2i = 2;
  const float* yv = v2s[v2i];
  const float* wt = ws + OFF_WT + c;
  float sd = 0.f, s1 = 0.f, s2 = 0.f;
#pragma unroll 4
  for (int h = 0; h < Hc; h++) {
    float wq = wt[(size_t)h * 64];
    float x = v1s[h], y = yv[h];
    float t1 = wq * x, t2 = wq * y;
    sd += t1 * y;
    s1 += t1 * x;
    s2 += t2 * y;
  }
  float mm = sd / fmaxf(sqrtf(s1) * sqrtf(s2), EPSF);
  int ch;
  if (c < 20) ch = 3 + c;
  else if (c < 40) ch = 64 + (c - 20);
  else if (c < 60) ch = 85 + (c - 40);
  else if (c == 60) ch = 2;
  else if (c == 61) ch = 63;
  else if (c == 62) ch = 84;
  else ch = -1;
  if (ch >= 0) {
    size_t orow = (size_t)side * Bc * Lc * NCHc + ((size_t)b * Lc + l) * NCHc;
    storef(out, orow + ch, mm, isb);
  }
}

extern "C" void kernel_launch(void* const* d_in, const int* in_sizes, int n_in,
                              void* d_out, int out_size, void* d_ws, size_t ws_size,
                              hipStream_t stream) {
  const void* ctx_p = d_in[0];
  const void* mask_p = d_in[1];
  const void* ctx_h = d_in[2];
  const void* mask_h = d_in[3];
  const void* w_full = d_in[4];
  const void* w_mp = d_in[5];
  const void* w_att = d_in[6];
  const void* w_maxatt = d_in[7];
  float* ws = (float*)d_ws;

  convert_kernel<<<145, 256, 0, stream>>>(mask_p, mask_h, w_full, w_mp, w_att, w_maxatt, ws);
  prep_kernel<<<2 * Bc * Lc, 64, 0, stream>>>(ctx_p, ctx_h, ws);
  lastlen_kernel<<<2 * Bc, 64, 0, stream>>>(ctx_p, ctx_h, ws);
  cos_kernel<<<Bc * Lc, 128, 0, stream>>>(ws);
  cosred_kernel<<<Bc * Lc, 128, 0, stream>>>(ws + OFF_COS, ws + OFF_MASKHF,
                                             ws + OFF_MASKPF, ws + OFF_LENH,
                                             ws + OFF_ROWSUM, d_out, 0, ws + OFF_FLAG);
  cosred_kernel<<<Bc * Lc, 128, 0, stream>>>(ws + OFF_COST, ws + OFF_MASKPF,
                                             ws + OFF_MASKHF, ws + OFF_LENP,
                                             ws + OFF_COLSUM, d_out,
                                             (size_t)Bc * Lc * NCHc, ws + OFF_FLAG);
  att_kernel<<<Bc * Lc, 256, 0, stream>>>(ws + OFF_COS, ws + OFF_CHM, ws + OFF_ROWSUM,
                                          ws + OFF_MASKHF, ws + OFF_MASKPF,
                                          ws + OFF_AMEANH, ws + OFF_AMAXH);
  att_kernel<<<Bc * Lc, 256, 0, stream>>>(ws + OFF_COST, ws + OFF_CPM, ws + OFF_COLSUM,
                                          ws + OFF_MASKPF, ws + OFF_MASKHF,
                                          ws + OFF_AMEANP, ws + OFF_AMAXP);
  maxpool_kernel<<<dim3(4, NPc, Bc), 64, 0, stream>>>(ws);
  mpfin_kernel<<<640, 256, 0, stream>>>(ws, d_out);
  mpm_kernel<<<2 * Bc * Lc, 64, 0, stream>>>(ws, d_out);
}

// Round 5
// 244.580 us; speedup vs baseline: 1.2244x; 1.2244x over previous
//
#include <hip/hip_runtime.h>
#include <hip/hip_bf16.h>

// BiMPM matching, B=32, L=128, H=200, NP=20.
// Input/output dtype (bf16 vs f32) detected at runtime from mask_p[0] bit
// pattern. All compute in f32 via ws; maxpool GEMM uses bf16 MFMA with
// fragments loaded directly from global (no LDS), per-np w^2 applied in
// registers (|dcos| <= ~2^-8, under the 1.57e-2 threshold).
// Output: mv_p (32,128,105), mv_h same.

#define EPSF 1e-8f
#define NEGF -1e7f

constexpr int Bc = 32, Lc = 128, Hc = 200, NPc = 20, NCHc = 105;
constexpr int KP = 224;    // maxpool padded K (7 x 32)
constexpr size_t SLH = (size_t)Bc * Lc * Hc;   // 819200
constexpr size_t SLL = (size_t)Bc * Lc * Lc;   // 524288

// workspace layout (floats)
constexpr size_t OFF_CPM    = 0;
constexpr size_t OFF_CHM    = OFF_CPM + SLH;
constexpr size_t OFF_CHMT   = OFF_CHM + SLH;       // [b][h][l]
constexpr size_t OFF_COS    = OFF_CHMT + SLH;      // [b][p][q]
constexpr size_t OFF_COST   = OFF_COS + SLL;       // [b][q][p]
constexpr size_t OFF_AMEANH = OFF_COST + SLL;      // (b,Lp,H)
constexpr size_t OFF_AMAXH  = OFF_AMEANH + SLH;
constexpr size_t OFF_AMEANP = OFF_AMAXH + SLH;     // (b,Lh,H)
constexpr size_t OFF_AMAXP  = OFF_AMEANP + SLH;
constexpr size_t OFF_NORMP  = OFF_AMAXP + SLH;
constexpr size_t OFF_NORMH  = OFF_NORMP + (size_t)Bc * Lc;
constexpr size_t OFF_ROWSUM = OFF_NORMH + (size_t)Bc * Lc;
constexpr size_t OFF_COLSUM = OFF_ROWSUM + (size_t)Bc * Lc;
constexpr size_t OFF_LENP   = OFF_COLSUM + (size_t)Bc * Lc;
constexpr size_t OFF_LENH   = OFF_LENP + Bc;
constexpr size_t OFF_LASTP  = OFF_LENH + Bc;
constexpr size_t OFF_LASTH  = OFF_LASTP + (size_t)Bc * Hc;
constexpr size_t OFF_NWP    = OFF_LASTH + (size_t)Bc * Hc;  // [b][np][l]
constexpr size_t OFF_NWH    = OFF_NWP + (size_t)Bc * NPc * Lc;
constexpr size_t OFF_MASKPF = OFF_NWH + (size_t)Bc * NPc * Lc;
constexpr size_t OFF_MASKHF = OFF_MASKPF + (size_t)Bc * Lc;
constexpr size_t OFF_WFULL  = OFF_MASKHF + (size_t)Bc * Lc;
constexpr size_t OFF_WMP    = OFF_WFULL + (size_t)NPc * Hc;
constexpr size_t OFF_WATT   = OFF_WMP + (size_t)NPc * Hc;
constexpr size_t OFF_WMATT  = OFF_WATT + (size_t)NPc * Hc;
constexpr size_t OFF_FLAG   = OFF_WMATT + (size_t)NPc * Hc;
constexpr size_t OFF_WT     = OFF_FLAG + 64;                // [h][64] squared-weights table
constexpr size_t OFF_RPMAX  = OFF_WT + (size_t)Hc * 64;     // [qi][b][np][p]
constexpr size_t OFF_RPSUM  = OFF_RPMAX + 2 * (size_t)Bc * NPc * Lc;
constexpr size_t OFF_CPMAX  = OFF_RPSUM + 2 * (size_t)Bc * NPc * Lc;  // [pi][b][np][q]
constexpr size_t OFF_CPSUM  = OFF_CPMAX + 2 * (size_t)Bc * NPc * Lc;
constexpr size_t OFF_CHB    = OFF_CPSUM + 2 * (size_t)Bc * NPc * Lc;  // bf16 [b][l][KP]
constexpr size_t OFF_CPB    = OFF_CHB + ((size_t)Bc * Lc * KP) / 2;   // bf16 [b][l][KP]
constexpr size_t OFF_W2K    = OFF_CPB + ((size_t)Bc * Lc * KP) / 2;   // f32 [np][KP]
constexpr size_t WS_FLOATS  = OFF_W2K + (size_t)NPc * KP;   // ~8.6M floats (~34.4 MB)

typedef __attribute__((ext_vector_type(8))) short short8v;
typedef __attribute__((ext_vector_type(4))) short short4v;
typedef __attribute__((ext_vector_type(4))) float float4v;

__device__ __forceinline__ float loadf(const void* p, size_t i, int isb) {
  if (isb) return __bfloat162float(((const __hip_bfloat16*)p)[i]);
  return ((const float*)p)[i];
}

__device__ __forceinline__ void storef(void* out, size_t i, float v, int isb) {
  if (isb) ((__hip_bfloat16*)out)[i] = __float2bfloat16(v);
  else ((float*)out)[i] = v;
}

__device__ __forceinline__ short b2s(float f) {
  __hip_bfloat16 h = __float2bfloat16(f);
  union { __hip_bfloat16 b; short s; } u;
  u.b = h;
  return u.s;
}

// unpack bf16 lane, scale by w (f32), repack to bf16
__device__ __forceinline__ short8v weight8(short8v a, float4v w0, float4v w1) {
  short8v r;
#pragma unroll
  for (int e = 0; e < 8; e++) {
    union { unsigned u; float f; } c;
    c.u = ((unsigned)(unsigned short)a[e]) << 16;
    float w = (e < 4) ? w0[e] : w1[e - 4];
    r[e] = b2s(c.f * w);
  }
  return r;
}

// ---------------- dtype detect + convert small inputs + tables ---------------
__global__ void convert_kernel(const void* mp, const void* mh, const void* wf,
                               const void* wmp, const void* watt, const void* wma,
                               float* __restrict__ ws) {
  int isb = (((const unsigned short*)mp)[0] == 0x3F80u) ? 1 : 0;
  int g = blockIdx.x * 256 + threadIdx.x;
  if (g == 0) ws[OFF_FLAG] = (float)isb;
  const int n0 = Bc * Lc;          // 4096
  const int nw = NPc * Hc;         // 4000
  if (g < n0) {
    ws[OFF_MASKPF + g] = loadf(mp, g, isb);
  } else if (g < 2 * n0) {
    ws[OFF_MASKHF + (g - n0)] = loadf(mh, g - n0, isb);
  } else if (g < 2 * n0 + 4 * nw) {
    int r = g - 2 * n0;
    int seg = r / nw, off = r % nw;
    if (seg == 0) ws[OFF_WFULL + off] = loadf(wf, off, isb);
    else if (seg == 1) ws[OFF_WMP + off] = loadf(wmp, off, isb);
    else if (seg == 2) ws[OFF_WATT + off] = loadf(watt, off, isb);
    else ws[OFF_WMATT + off] = loadf(wma, off, isb);
  } else if (g < 2 * n0 + 4 * nw + Hc * 64) {
    int r = g - (2 * n0 + 4 * nw);
    int h = r >> 6, c = r & 63;
    float w = 1.0f;
    if (c < 20) w = loadf(wf, (size_t)c * Hc + h, isb);
    else if (c < 40) w = loadf(watt, (size_t)(c - 20) * Hc + h, isb);
    else if (c < 60) w = loadf(wma, (size_t)(c - 40) * Hc + h, isb);
    ws[OFF_WT + r] = w * w;
  } else if (g < 2 * n0 + 4 * nw + Hc * 64 + NPc * KP) {
    int r = g - (2 * n0 + 4 * nw + Hc * 64);
    int np_ = r / KP, k = r % KP;
    float w = (k < Hc) ? loadf(wmp, (size_t)np_ * Hc + k, isb) : 0.f;
    ws[OFF_W2K + r] = w * w;
  }
}

// ---------------- prep: masked copies, chmT, cpb/chb(bf16), norms, w-norms ---
__global__ void prep_kernel(const void* __restrict__ ctx_p,
                            const void* __restrict__ ctx_h,
                            float* __restrict__ ws) {
  int bid = blockIdx.x;
  int side = bid >> 12;
  int bl = bid & 4095;
  int b = bl >> 7, l = bl & 127;
  int lane = threadIdx.x;      // 64
  int isb = ws[OFF_FLAG] > 0.5f;
  const void* ctx = side ? ctx_h : ctx_p;
  const float* mask = ws + (side ? OFF_MASKHF : OFF_MASKPF);
  float mk = mask[b * Lc + l];
  size_t rowbase = ((size_t)b * Lc + l) * Hc;
  float* cm = ws + (side ? OFF_CHM : OFF_CPM) + rowbase;
  __hip_bfloat16* cb16 = (__hip_bfloat16*)(ws + (side ? OFF_CHB : OFF_CPB));
  size_t cb = ((size_t)b * Lc + l) * KP;

  float v[4];
  float ss = 0.f;
  for (int i = 0; i < 4; i++) {
    int h = lane + 64 * i;
    float x = 0.f;
    if (h < Hc) {
      x = loadf(ctx, rowbase + h, isb) * mk;
      cm[h] = x;
      if (side) ws[OFF_CHMT + ((size_t)b * Hc + h) * Lc + l] = x;
      cb16[cb + h] = __float2bfloat16(x);
    } else if (h < KP) {
      cb16[cb + h] = __float2bfloat16(0.f);
    }
    v[i] = x;
    ss += x * x;
  }
  for (int o = 32; o > 0; o >>= 1) ss += __shfl_xor(ss, o);
  if (lane == 0) ws[(side ? OFF_NORMH : OFF_NORMP) + b * Lc + l] = sqrtf(ss);

  const float* wmpf = ws + OFF_WMP;
  float* nw = ws + (side ? OFF_NWH : OFF_NWP) + (size_t)b * NPc * Lc;
  for (int np_ = 0; np_ < NPc; np_++) {
    float s = 0.f;
    for (int i = 0; i < 4; i++) {
      int h = lane + 64 * i;
      if (h < Hc) {
        float w = wmpf[np_ * Hc + h];
        float wx = w * v[i];
        s += wx * wx;
      }
    }
    for (int o = 32; o > 0; o >>= 1) s += __shfl_xor(s, o);
    if (lane == 0) nw[np_ * Lc + l] = sqrtf(s);
  }
}

// ---------------- lengths + last-token vectors -------------------------------
__global__ void lastlen_kernel(const void* __restrict__ ctx_p,
                               const void* __restrict__ ctx_h,
                               float* __restrict__ ws) {
  int side = blockIdx.x >> 5, b = blockIdx.x & 31;
  int lane = threadIdx.x;  // 64
  int isb = ws[OFF_FLAG] > 0.5f;
  const float* mask = ws + (side ? OFF_MASKHF : OFF_MASKPF);
  const void* ctx = side ? ctx_h : ctx_p;
  float s = 0.f;
  for (int l = lane; l < Lc; l += 64) s += mask[b * Lc + l];
  for (int o = 32; o > 0; o >>= 1) s += __shfl_xor(s, o);
  if (lane == 0) ws[(side ? OFF_LENH : OFF_LENP) + b] = s;
  int idx = (int)(s + 0.5f) - 1;
  if (idx < 0) idx = 0;
  float mk = mask[b * Lc + idx];
  float* lastv = ws + (side ? OFF_LASTH : OFF_LASTP) + (size_t)b * Hc;
  for (int h = lane; h < Hc; h += 64)
    lastv[h] = loadf(ctx, ((size_t)b * Lc + idx) * Hc + h, isb) * mk;
}

// ---------------- cos matrix (and transpose) ---------------------------------
__global__ void cos_kernel(float* __restrict__ ws) {
  int b = blockIdx.x >> 7, p = blockIdx.x & 127;
  int t = threadIdx.x;  // 128
  __shared__ float v1s[Hc];
  for (int h = t; h < Hc; h += 128) v1s[h] = ws[OFF_CPM + ((size_t)b * Lc + p) * Hc + h];
  __syncthreads();
  const float* bT = ws + OFF_CHMT + (size_t)b * Hc * Lc;
  float acc = 0.f;
#pragma unroll 8
  for (int h = 0; h < Hc; h++) acc += v1s[h] * bT[(size_t)h * Lc + t];
  float denom = fmaxf(ws[OFF_NORMP + b * Lc + p] * ws[OFF_NORMH + b * Lc + t], EPSF);
  float cv = acc / denom;
  ws[OFF_COS + ((size_t)b * Lc + p) * Lc + t] = cv;
  ws[OFF_COST + ((size_t)b * Lc + t) * Lc + p] = cv;
}

// ---------------- cos row reductions: channels 0,1 + row/col sums ------------
__global__ void cosred_kernel(const float* __restrict__ rows,
                              const float* __restrict__ maskLoop,
                              const float* __restrict__ maskRow,
                              const float* __restrict__ lenOther,
                              float* __restrict__ sumdst,
                              void* __restrict__ outbase, size_t obase,
                              const float* __restrict__ wsflag) {
  int b = blockIdx.x >> 7, r = blockIdx.x & 127;
  int t = threadIdx.x;  // 128
  int isb = wsflag[0] > 0.5f;
  float c = rows[((size_t)b * Lc + r) * Lc + t];
  float ml = maskLoop[b * Lc + t];
  float mval = (ml > 0.f) ? c : NEGF;
  float sval = c;
  for (int o = 32; o > 0; o >>= 1) {
    mval = fmaxf(mval, __shfl_xor(mval, o));
    sval += __shfl_xor(sval, o);
  }
  __shared__ float sm[2], ssm[2];
  if ((t & 63) == 0) { sm[t >> 6] = mval; ssm[t >> 6] = sval; }
  __syncthreads();
  if (t == 0) {
    float m = fmaxf(sm[0], sm[1]);
    float s = ssm[0] + ssm[1];
    sumdst[b * Lc + r] = s;
    float mr = maskRow[b * Lc + r];
    size_t orow = obase + ((size_t)b * Lc + r) * NCHc;
    storef(outbase, orow + 0, mr * m, isb);
    storef(outbase, orow + 1, mr * s / fmaxf(mr * lenOther[b], EPSF), isb);
  }
}

// ---------------- fused attentive mean + max ---------------------------------
__global__ void att_kernel(const float* __restrict__ cosrows,
                           const float* __restrict__ vsrc,
                           const float* __restrict__ denom,
                           const float* __restrict__ maskLoop,
                           const float* __restrict__ maskRow,
                           float* __restrict__ amean, float* __restrict__ amax) {
  int b = blockIdx.x >> 7, r = blockIdx.x & 127;
  int t = threadIdx.x;  // 256
  __shared__ float crow[Lc];
  __shared__ float mrow[Lc];
  if (t < Lc) {
    crow[t] = cosrows[((size_t)b * Lc + r) * Lc + t];
    mrow[t] = maskLoop[b * Lc + t];
  }
  __syncthreads();
  if (t < Hc) {
    float s = 0.f, m = NEGF;
    const float* vb = vsrc + (size_t)b * Lc * Hc + t;
#pragma unroll 4
    for (int q = 0; q < Lc; q++) {
      float pr = crow[q] * vb[(size_t)q * Hc];
      s += pr;
      if (mrow[q] > 0.f) m = fmaxf(m, pr);
    }
    float den = fmaxf(denom[b * Lc + r], EPSF);
    amean[((size_t)b * Lc + r) * Hc + t] = s / den;
    amax[((size_t)b * Lc + r) * Hc + t] = maskRow[b * Lc + r] * m;
  }
}

// ---------------- maxpool: 64x64x224 bf16-MFMA, no LDS, frag-direct ----------
__global__ __launch_bounds__(64, 3) void maxpool_kernel(float* __restrict__ ws) {
  int s = blockIdx.x;            // 0..3
  int np_ = blockIdx.y, b = blockIdx.z;
  int pi = s >> 1, qi = s & 1;
  int lane = threadIdx.x;        // 64, single wave
  int rsel = lane & 15, quad = lane >> 4;

  const short* Ab = (const short*)(ws + OFF_CPB)
                  + ((size_t)b * Lc + pi * 64 + rsel) * KP + quad * 8;
  const short* Bb = (const short*)(ws + OFF_CHB)
                  + ((size_t)b * Lc + qi * 64 + rsel) * KP + quad * 8;
  const float* w2k = ws + OFF_W2K + (size_t)np_ * KP + quad * 8;

  float4v acc[4][4];
  float4v zf = {0.f, 0.f, 0.f, 0.f};
#pragma unroll
  for (int i = 0; i < 4; i++)
#pragma unroll
    for (int j = 0; j < 4; j++) acc[i][j] = zf;

#pragma unroll
  for (int st = 0; st < 7; st++) {
    int k0 = st * 32;
    float4v w0 = *(const float4v*)(w2k + k0);
    float4v w1 = *(const float4v*)(w2k + k0 + 4);
    short8v bf4[4], af[4];
#pragma unroll
    for (int t = 0; t < 4; t++)
      bf4[t] = *(const short8v*)(Bb + (size_t)t * 16 * KP + k0);
#pragma unroll
    for (int t = 0; t < 4; t++) {
      short8v ar = *(const short8v*)(Ab + (size_t)t * 16 * KP + k0);
      af[t] = weight8(ar, w0, w1);
    }
#pragma unroll
    for (int i = 0; i < 4; i++)
#pragma unroll
      for (int j = 0; j < 4; j++)
        acc[i][j] = __builtin_amdgcn_mfma_f32_16x16x32_bf16(af[i], bf4[j], acc[i][j], 0, 0, 0);
  }

  // epilogue: v = acc / max(nwp*nwh, eps); masked max/mean partials, both axes
  const float* nwp = ws + OFF_NWP + ((size_t)b * NPc + np_) * Lc + pi * 64;
  const float* nwh = ws + OFF_NWH + ((size_t)b * NPc + np_) * Lc + qi * 64;
  const float* maskP = ws + OFF_MASKPF + b * Lc + pi * 64;
  const float* maskH = ws + OFF_MASKHF + b * Lc + qi * 64;
  float nhv[4], mhv[4], cmax[4], csum[4];
#pragma unroll
  for (int tj = 0; tj < 4; tj++) {
    int q = tj * 16 + rsel;
    nhv[tj] = nwh[q];
    mhv[tj] = maskH[q];
    cmax[tj] = NEGF;
    csum[tj] = 0.f;
  }
  size_t rbase = (((size_t)qi * Bc + b) * NPc + np_) * Lc + pi * 64;
  size_t cbase = (((size_t)pi * Bc + b) * NPc + np_) * Lc + qi * 64;
#pragma unroll
  for (int ti = 0; ti < 4; ti++) {
#pragma unroll
    for (int r = 0; r < 4; r++) {
      int p = ti * 16 + quad * 4 + r;
      float npv = nwp[p], mpv = maskP[p];
      float rm = NEGF, rs = 0.f;
#pragma unroll
      for (int tj = 0; tj < 4; tj++) {
        float v = acc[ti][tj][r] * __builtin_amdgcn_rcpf(fmaxf(npv * nhv[tj], EPSF));
        if (mhv[tj] > 0.f) rm = fmaxf(rm, v);
        rs += v * mhv[tj];
        if (mpv > 0.f) cmax[tj] = fmaxf(cmax[tj], v);
        csum[tj] += v * mpv;
      }
      // reduce over q within row p: lanes differing in bits 0-3 (col)
#pragma unroll
      for (int o = 1; o <= 8; o <<= 1) {
        rm = fmaxf(rm, __shfl_xor(rm, o));
        rs += __shfl_xor(rs, o);
      }
      if (rsel == 0) {
        ws[OFF_RPMAX + rbase + p] = rm;
        ws[OFF_RPSUM + rbase + p] = rs;
      }
    }
  }
  // reduce cols over p: lanes differing in bits 4-5 (quad)
#pragma unroll
  for (int tj = 0; tj < 4; tj++) {
#pragma unroll
    for (int o = 16; o <= 32; o <<= 1) {
      cmax[tj] = fmaxf(cmax[tj], __shfl_xor(cmax[tj], o));
      csum[tj] += __shfl_xor(csum[tj], o);
    }
  }
  if (quad == 0) {
#pragma unroll
    for (int tj = 0; tj < 4; tj++) {
      int q = tj * 16 + rsel;
      ws[OFF_CPMAX + cbase + q] = cmax[tj];
      ws[OFF_CPSUM + cbase + q] = csum[tj];
    }
  }
}

// ---------------- maxpool finalize: combine 2 partials, write channels -------
__global__ void mpfin_kernel(float* __restrict__ ws, void* __restrict__ out) {
  int g = blockIdx.x * 256 + threadIdx.x;  // 2*32*20*128 = 163840
  if (g >= 2 * Bc * NPc * Lc) return;
  int isb = ws[OFF_FLAG] > 0.5f;
  int l = g & 127;
  int r = g >> 7;
  int np_ = r % NPc;
  int t2 = r / NPc;
  int b = t2 & 31;
  int side = t2 >> 5;
  size_t i0 = (((size_t)0 * Bc + b) * NPc + np_) * Lc + l;
  size_t i1 = (((size_t)1 * Bc + b) * NPc + np_) * Lc + l;
  float m, sum, mk, len;
  if (side == 0) {
    m = fmaxf(ws[OFF_RPMAX + i0], ws[OFF_RPMAX + i1]);
    sum = ws[OFF_RPSUM + i0] + ws[OFF_RPSUM + i1];
    mk = ws[OFF_MASKPF + b * Lc + l];
    len = ws[OFF_LENH + b];
  } else {
    m = fmaxf(ws[OFF_CPMAX + i0], ws[OFF_CPMAX + i1]);
    sum = ws[OFF_CPSUM + i0] + ws[OFF_CPSUM + i1];
    mk = ws[OFF_MASKHF + b * Lc + l];
    len = ws[OFF_LENP + b];
  }
  size_t orow = (size_t)side * Bc * Lc * NCHc + ((size_t)b * Lc + l) * NCHc;
  storef(out, orow + 23 + np_, mk * m, isb);
  storef(out, orow + 43 + np_, mk * sum / fmaxf(mk * len, EPSF), isb);
}

// ---------------- mpm epilogue: lane-per-channel, no cross-lane --------------
__global__ __launch_bounds__(64) void mpm_kernel(float* __restrict__ ws,
                                                 void* __restrict__ out) {
  int bid = blockIdx.x;
  int side = bid >> 12;
  int b = (bid >> 7) & 31, l = bid & 127;
  int c = threadIdx.x;  // 64: lane = channel
  int isb = ws[OFF_FLAG] > 0.5f;
  __shared__ float v1s[Hc];
  __shared__ float v2s[3][Hc];
  const float* v1 = ws + (side ? OFF_CHM : OFF_CPM) + ((size_t)b * Lc + l) * Hc;
  const float* v2f = ws + (side ? OFF_LASTP : OFF_LASTH) + (size_t)b * Hc;
  const float* v2a = ws + (side ? OFF_AMEANP : OFF_AMEANH) + ((size_t)b * Lc + l) * Hc;
  const float* v2m = ws + (side ? OFF_AMAXP : OFF_AMAXH) + ((size_t)b * Lc + l) * Hc;
  for (int h = c; h < Hc; h += 64) {
    v1s[h] = v1[h];
    v2s[0][h] = v2f[h];
    v2s[1][h] = v2a[h];
    v2s[2][h] = v2m[h];
  }
  __syncthreads();
  int v2i = (c < 20) ? 0 : (c < 40) ? 1 : (c < 60) ? 2 : (c - 60);
  if (v2i > 2) v2i = 2;
  const float* yv = v2s[v2i];
  const float* wt = ws + OFF_WT + c;
  float sd = 0.f, s1 = 0.f, s2 = 0.f;
#pragma unroll 4
  for (int h = 0; h < Hc; h++) {
    float wq = wt[(size_t)h * 64];
    float x = v1s[h], y = yv[h];
    float t1 = wq * x, t2 = wq * y;
    sd += t1 * y;
    s1 += t1 * x;
    s2 += t2 * y;
  }
  float mm = sd / fmaxf(sqrtf(s1) * sqrtf(s2), EPSF);
  int ch;
  if (c < 20) ch = 3 + c;
  else if (c < 40) ch = 64 + (c - 20);
  else if (c < 60) ch = 85 + (c - 40);
  else if (c == 60) ch = 2;
  else if (c == 61) ch = 63;
  else if (c == 62) ch = 84;
  else ch = -1;
  if (ch >= 0) {
    size_t orow = (size_t)side * Bc * Lc + (size_t)l;
    orow = ((size_t)side * Bc * Lc + (size_t)b * Lc + l) * NCHc;
    storef(out, orow + ch, mm, isb);
  }
}

extern "C" void kernel_launch(void* const* d_in, const int* in_sizes, int n_in,
                              void* d_out, int out_size, void* d_ws, size_t ws_size,
                              hipStream_t stream) {
  const void* ctx_p = d_in[0];
  const void* mask_p = d_in[1];
  const void* ctx_h = d_in[2];
  const void* mask_h = d_in[3];
  const void* w_full = d_in[4];
  const void* w_mp = d_in[5];
  const void* w_att = d_in[6];
  const void* w_maxatt = d_in[7];
  float* ws = (float*)d_ws;

  convert_kernel<<<162, 256, 0, stream>>>(mask_p, mask_h, w_full, w_mp, w_att, w_maxatt, ws);
  prep_kernel<<<2 * Bc * Lc, 64, 0, stream>>>(ctx_p, ctx_h, ws);
  lastlen_kernel<<<2 * Bc, 64, 0, stream>>>(ctx_p, ctx_h, ws);
  cos_kernel<<<Bc * Lc, 128, 0, stream>>>(ws);
  cosred_kernel<<<Bc * Lc, 128, 0, stream>>>(ws + OFF_COS, ws + OFF_MASKHF,
                                             ws + OFF_MASKPF, ws + OFF_LENH,
                                             ws + OFF_ROWSUM, d_out, 0, ws + OFF_FLAG);
  cosred_kernel<<<Bc * Lc, 128, 0, stream>>>(ws + OFF_COST, ws + OFF_MASKPF,
                                             ws + OFF_MASKHF, ws + OFF_LENP,
                                             ws + OFF_COLSUM, d_out,
                                             (size_t)Bc * Lc * NCHc, ws + OFF_FLAG);
  att_kernel<<<Bc * Lc, 256, 0, stream>>>(ws + OFF_COS, ws + OFF_CHM, ws + OFF_ROWSUM,
                                          ws + OFF_MASKHF, ws + OFF_MASKPF,
                                          ws + OFF_AMEANH, ws + OFF_AMAXH);
  att_kernel<<<Bc * Lc, 256, 0, stream>>>(ws + OFF_COST, ws + OFF_CPM, ws + OFF_COLSUM,
                                          ws + OFF_MASKPF, ws + OFF_MASKHF,
                                          ws + OFF_AMEANP, ws + OFF_AMAXP);
  maxpool_kernel<<<dim3(4, NPc, Bc), 64, 0, stream>>>(ws);
  mpfin_kernel<<<640, 256, 0, stream>>>(ws, d_out);
  mpm_kernel<<<2 * Bc * Lc, 64, 0, stream>>>(ws, d_out);
}

// Round 6
// 211.570 us; speedup vs baseline: 1.4155x; 1.1560x over previous
//
#include <hip/hip_runtime.h>
#include <hip/hip_bf16.h>

// BiMPM matching, B=32, L=128, H=200, NP=20.
// Input/output dtype (bf16 vs f32) detected at runtime from mask_p[0] bit
// pattern. All compute in f32 via ws; maxpool GEMM uses bf16 MFMA with
// fragments loaded directly from global (no LDS), per-np w^2 applied in
// registers. 6 launches: convert(+lastlen), prep, cos, att(+ch01), maxpool,
// mpm(+mpfin). Output: mv_p (32,128,105), mv_h same.

#define EPSF 1e-8f
#define NEGF -1e7f

constexpr int Bc = 32, Lc = 128, Hc = 200, NPc = 20, NCHc = 105;
constexpr int KP = 224;    // maxpool padded K (7 x 32)
constexpr size_t SLH = (size_t)Bc * Lc * Hc;   // 819200
constexpr size_t SLL = (size_t)Bc * Lc * Lc;   // 524288

// workspace layout (floats)
constexpr size_t OFF_CPM    = 0;
constexpr size_t OFF_CHM    = OFF_CPM + SLH;
constexpr size_t OFF_CHMT   = OFF_CHM + SLH;       // [b][h][l]
constexpr size_t OFF_COS    = OFF_CHMT + SLH;      // [b][p][q]
constexpr size_t OFF_COST   = OFF_COS + SLL;       // [b][q][p]
constexpr size_t OFF_AMEANH = OFF_COST + SLL;      // (b,Lp,H)
constexpr size_t OFF_AMAXH  = OFF_AMEANH + SLH;
constexpr size_t OFF_AMEANP = OFF_AMAXH + SLH;     // (b,Lh,H)
constexpr size_t OFF_AMAXP  = OFF_AMEANP + SLH;
constexpr size_t OFF_NORMP  = OFF_AMAXP + SLH;
constexpr size_t OFF_NORMH  = OFF_NORMP + (size_t)Bc * Lc;
constexpr size_t OFF_LENP   = OFF_NORMH + (size_t)Bc * Lc;
constexpr size_t OFF_LENH   = OFF_LENP + Bc;
constexpr size_t OFF_LASTP  = OFF_LENH + Bc;
constexpr size_t OFF_LASTH  = OFF_LASTP + (size_t)Bc * Hc;
constexpr size_t OFF_NWP    = OFF_LASTH + (size_t)Bc * Hc;  // [b][np][l]
constexpr size_t OFF_NWH    = OFF_NWP + (size_t)Bc * NPc * Lc;
constexpr size_t OFF_MASKPF = OFF_NWH + (size_t)Bc * NPc * Lc;
constexpr size_t OFF_MASKHF = OFF_MASKPF + (size_t)Bc * Lc;
constexpr size_t OFF_WFULL  = OFF_MASKHF + (size_t)Bc * Lc;
constexpr size_t OFF_WMP    = OFF_WFULL + (size_t)NPc * Hc;
constexpr size_t OFF_WATT   = OFF_WMP + (size_t)NPc * Hc;
constexpr size_t OFF_WMATT  = OFF_WATT + (size_t)NPc * Hc;
constexpr size_t OFF_FLAG   = OFF_WMATT + (size_t)NPc * Hc;
constexpr size_t OFF_WT     = OFF_FLAG + 64;                // [h][64] squared-weights table
constexpr size_t OFF_RPMAX  = OFF_WT + (size_t)Hc * 64;     // [qi][b][np][p]
constexpr size_t OFF_RPSUM  = OFF_RPMAX + 2 * (size_t)Bc * NPc * Lc;
constexpr size_t OFF_CPMAX  = OFF_RPSUM + 2 * (size_t)Bc * NPc * Lc;  // [pi][b][np][q]
constexpr size_t OFF_CPSUM  = OFF_CPMAX + 2 * (size_t)Bc * NPc * Lc;
constexpr size_t OFF_CHB    = OFF_CPSUM + 2 * (size_t)Bc * NPc * Lc;  // bf16 [b][l][KP]
constexpr size_t OFF_CPB    = OFF_CHB + ((size_t)Bc * Lc * KP) / 2;   // bf16 [b][l][KP]
constexpr size_t OFF_W2K    = OFF_CPB + ((size_t)Bc * Lc * KP) / 2;   // f32 [np][KP]
constexpr size_t WS_FLOATS  = OFF_W2K + (size_t)NPc * KP;   // ~8.6M floats (~34.4 MB)

typedef __attribute__((ext_vector_type(8))) short short8v;
typedef __attribute__((ext_vector_type(4))) short short4v;
typedef __attribute__((ext_vector_type(4))) float float4v;

__device__ __forceinline__ float loadf(const void* p, size_t i, int isb) {
  if (isb) return __bfloat162float(((const __hip_bfloat16*)p)[i]);
  return ((const float*)p)[i];
}

__device__ __forceinline__ void storef(void* out, size_t i, float v, int isb) {
  if (isb) ((__hip_bfloat16*)out)[i] = __float2bfloat16(v);
  else ((float*)out)[i] = v;
}

__device__ __forceinline__ short b2s(float f) {
  __hip_bfloat16 h = __float2bfloat16(f);
  union { __hip_bfloat16 b; short s; } u;
  u.b = h;
  return u.s;
}

// unpack bf16 lane, scale by w (f32), repack to bf16
__device__ __forceinline__ short8v weight8(short8v a, float4v w0, float4v w1) {
  short8v r;
#pragma unroll
  for (int e = 0; e < 8; e++) {
    union { unsigned u; float f; } c;
    c.u = ((unsigned)(unsigned short)a[e]) << 16;
    float w = (e < 4) ? w0[e] : w1[e - 4];
    r[e] = b2s(c.f * w);
  }
  return r;
}

// ---------------- convert: dtype detect, small-input f32 copies, tables,
// ---------------- plus fused lastlen (lengths + last-token vectors) ----------
__global__ void convert_kernel(const void* cp_, const void* mp, const void* ch_,
                               const void* mh, const void* wf, const void* wmp,
                               const void* watt, const void* wma,
                               float* __restrict__ ws) {
  int isb = (((const unsigned short*)mp)[0] == 0x3F80u) ? 1 : 0;
  int bid = blockIdx.x;
  const int n0 = Bc * Lc;          // 4096
  const int nw = NPc * Hc;         // 4000
  if (bid >= 162) {
    // lastlen: 16 blocks x 4 (side,b) pairs, one wave per pair
    int t = threadIdx.x;
    int idx = (bid - 162) * 4 + (t >> 6);   // 0..63
    int side = idx >> 5, b = idx & 31;
    int lane = t & 63;
    const void* mask = side ? mh : mp;
    const void* ctx = side ? ch_ : cp_;
    float s = 0.f;
    for (int l = lane; l < Lc; l += 64) s += loadf(mask, b * Lc + l, isb);
    for (int o = 32; o > 0; o >>= 1) s += __shfl_xor(s, o);
    if (lane == 0) ws[(side ? OFF_LENH : OFF_LENP) + b] = s;
    int lidx = (int)(s + 0.5f) - 1;
    if (lidx < 0) lidx = 0;
    float mk = loadf(mask, b * Lc + lidx, isb);
    float* lastv = ws + (side ? OFF_LASTH : OFF_LASTP) + (size_t)b * Hc;
    for (int h = lane; h < Hc; h += 64)
      lastv[h] = loadf(ctx, ((size_t)b * Lc + lidx) * Hc + h, isb) * mk;
    return;
  }
  int g = bid * 256 + threadIdx.x;
  if (g == 0) ws[OFF_FLAG] = (float)isb;
  if (g < n0) {
    ws[OFF_MASKPF + g] = loadf(mp, g, isb);
  } else if (g < 2 * n0) {
    ws[OFF_MASKHF + (g - n0)] = loadf(mh, g - n0, isb);
  } else if (g < 2 * n0 + 4 * nw) {
    int r = g - 2 * n0;
    int seg = r / nw, off = r % nw;
    if (seg == 0) ws[OFF_WFULL + off] = loadf(wf, off, isb);
    else if (seg == 1) ws[OFF_WMP + off] = loadf(wmp, off, isb);
    else if (seg == 2) ws[OFF_WATT + off] = loadf(watt, off, isb);
    else ws[OFF_WMATT + off] = loadf(wma, off, isb);
  } else if (g < 2 * n0 + 4 * nw + Hc * 64) {
    int r = g - (2 * n0 + 4 * nw);
    int h = r >> 6, c = r & 63;
    float w = 1.0f;
    if (c < 20) w = loadf(wf, (size_t)c * Hc + h, isb);
    else if (c < 40) w = loadf(watt, (size_t)(c - 20) * Hc + h, isb);
    else if (c < 60) w = loadf(wma, (size_t)(c - 40) * Hc + h, isb);
    ws[OFF_WT + r] = w * w;
  } else if (g < 2 * n0 + 4 * nw + Hc * 64 + NPc * KP) {
    int r = g - (2 * n0 + 4 * nw + Hc * 64);
    int np_ = r / KP, k = r % KP;
    float w = (k < Hc) ? loadf(wmp, (size_t)np_ * Hc + k, isb) : 0.f;
    ws[OFF_W2K + r] = w * w;
  }
}

// ---------------- prep: masked copies, chmT, cpb/chb(bf16), norms, w-norms ---
__global__ void prep_kernel(const void* __restrict__ ctx_p,
                            const void* __restrict__ ctx_h,
                            float* __restrict__ ws) {
  int bid = blockIdx.x;
  int side = bid >> 12;
  int bl = bid & 4095;
  int b = bl >> 7, l = bl & 127;
  int lane = threadIdx.x;      // 64
  int isb = ws[OFF_FLAG] > 0.5f;
  const void* ctx = side ? ctx_h : ctx_p;
  const float* mask = ws + (side ? OFF_MASKHF : OFF_MASKPF);
  float mk = mask[b * Lc + l];
  size_t rowbase = ((size_t)b * Lc + l) * Hc;
  float* cm = ws + (side ? OFF_CHM : OFF_CPM) + rowbase;
  __hip_bfloat16* cb16 = (__hip_bfloat16*)(ws + (side ? OFF_CHB : OFF_CPB));
  size_t cb = ((size_t)b * Lc + l) * KP;

  float v[4];
  float ss = 0.f;
  for (int i = 0; i < 4; i++) {
    int h = lane + 64 * i;
    float x = 0.f;
    if (h < Hc) {
      x = loadf(ctx, rowbase + h, isb) * mk;
      cm[h] = x;
      if (side) ws[OFF_CHMT + ((size_t)b * Hc + h) * Lc + l] = x;
      cb16[cb + h] = __float2bfloat16(x);
    } else if (h < KP) {
      cb16[cb + h] = __float2bfloat16(0.f);
    }
    v[i] = x;
    ss += x * x;
  }
  for (int o = 32; o > 0; o >>= 1) ss += __shfl_xor(ss, o);
  if (lane == 0) ws[(side ? OFF_NORMH : OFF_NORMP) + b * Lc + l] = sqrtf(ss);

  const float* wmpf = ws + OFF_WMP;
  float* nw = ws + (side ? OFF_NWH : OFF_NWP) + (size_t)b * NPc * Lc;
  for (int np_ = 0; np_ < NPc; np_++) {
    float s = 0.f;
    for (int i = 0; i < 4; i++) {
      int h = lane + 64 * i;
      if (h < Hc) {
        float w = wmpf[np_ * Hc + h];
        float wx = w * v[i];
        s += wx * wx;
      }
    }
    for (int o = 32; o > 0; o >>= 1) s += __shfl_xor(s, o);
    if (lane == 0) nw[np_ * Lc + l] = sqrtf(s);
  }
}

// ---------------- cos matrix (and transpose) ---------------------------------
__global__ void cos_kernel(float* __restrict__ ws) {
  int b = blockIdx.x >> 7, p = blockIdx.x & 127;
  int t = threadIdx.x;  // 128
  __shared__ float v1s[Hc];
  for (int h = t; h < Hc; h += 128) v1s[h] = ws[OFF_CPM + ((size_t)b * Lc + p) * Hc + h];
  __syncthreads();
  const float* bT = ws + OFF_CHMT + (size_t)b * Hc * Lc;
  float acc = 0.f;
#pragma unroll 8
  for (int h = 0; h < Hc; h++) acc += v1s[h] * bT[(size_t)h * Lc + t];
  float denom = fmaxf(ws[OFF_NORMP + b * Lc + p] * ws[OFF_NORMH + b * Lc + t], EPSF);
  float cv = acc / denom;
  ws[OFF_COS + ((size_t)b * Lc + p) * Lc + t] = cv;
  ws[OFF_COST + ((size_t)b * Lc + t) * Lc + p] = cv;
}

// ---------------- fused attentive mean+max, 4 rows/block, + ch0/1 ------------
__global__ __launch_bounds__(256) void att_kernel(float* __restrict__ ws,
                                                  void* __restrict__ out) {
  int side = blockIdx.z;
  int b = blockIdx.y;
  int r0 = blockIdx.x * 4;
  int t = threadIdx.x;  // 256
  int isb = ws[OFF_FLAG] > 0.5f;
  const float* cosrows = ws + (side ? OFF_COST : OFF_COS) + ((size_t)b * Lc + r0) * Lc;
  const float* vsrc = ws + (side ? OFF_CPM : OFF_CHM) + (size_t)b * Lc * Hc;
  const float* maskLoop = ws + (side ? OFF_MASKPF : OFF_MASKHF) + b * Lc;
  const float* maskRow = ws + (side ? OFF_MASKHF : OFF_MASKPF) + b * Lc;
  float lenOther = ws[(side ? OFF_LENP : OFF_LENH) + b];
  float* amean = ws + (side ? OFF_AMEANP : OFF_AMEANH) + ((size_t)b * Lc + r0) * Hc;
  float* amax = ws + (side ? OFF_AMAXP : OFF_AMAXH) + ((size_t)b * Lc + r0) * Hc;

  __shared__ float crow[4][Lc];
  __shared__ float mneg[Lc];
  __shared__ float dens[4];
  for (int i = t; i < 4 * Lc; i += 256) crow[i >> 7][i & 127] = cosrows[i];
  if (t < Lc) mneg[t] = (maskLoop[t] > 0.f) ? 0.f : -1e30f;
  __syncthreads();

  // per-row stats: wave w handles row r0+w  -> denom + out channels 0,1
  int wv = t >> 6, lane = t & 63;
  {
    float x1 = crow[wv][lane], x2 = crow[wv][lane + 64];
    float sv = x1 + x2;
    float mv = fmaxf(x1 + mneg[lane], x2 + mneg[lane + 64]);
    for (int o = 32; o > 0; o >>= 1) {
      sv += __shfl_xor(sv, o);
      mv = fmaxf(mv, __shfl_xor(mv, o));
    }
    if (lane == 0) {
      dens[wv] = sv;
      float mr = maskRow[r0 + wv];
      size_t orow = (size_t)side * Bc * Lc * NCHc + ((size_t)b * Lc + r0 + wv) * NCHc;
      storef(out, orow + 0, mr * mv, isb);
      storef(out, orow + 1, mr * sv / fmaxf(mr * lenOther, EPSF), isb);
    }
  }
  __syncthreads();

  if (t < Hc) {
    float s0 = 0.f, s1 = 0.f, s2 = 0.f, s3 = 0.f;
    float m0 = NEGF, m1 = NEGF, m2 = NEGF, m3 = NEGF;
    const float* vb = vsrc + t;
#pragma unroll 4
    for (int q = 0; q < Lc; q++) {
      float pr = vb[(size_t)q * Hc];
      float mn = mneg[q];
      float v0 = crow[0][q] * pr; s0 += v0; m0 = fmaxf(m0, v0 + mn);
      float v1 = crow[1][q] * pr; s1 += v1; m1 = fmaxf(m1, v1 + mn);
      float v2 = crow[2][q] * pr; s2 += v2; m2 = fmaxf(m2, v2 + mn);
      float v3 = crow[3][q] * pr; s3 += v3; m3 = fmaxf(m3, v3 + mn);
    }
    amean[0 * Hc + t] = s0 / fmaxf(dens[0], EPSF);
    amean[1 * Hc + t] = s1 / fmaxf(dens[1], EPSF);
    amean[2 * Hc + t] = s2 / fmaxf(dens[2], EPSF);
    amean[3 * Hc + t] = s3 / fmaxf(dens[3], EPSF);
    amax[0 * Hc + t] = maskRow[r0 + 0] * m0;
    amax[1 * Hc + t] = maskRow[r0 + 1] * m1;
    amax[2 * Hc + t] = maskRow[r0 + 2] * m2;
    amax[3 * Hc + t] = maskRow[r0 + 3] * m3;
  }
}

// ---------------- maxpool: 64x64x224 bf16-MFMA, no LDS, frag-direct ----------
__global__ __launch_bounds__(64, 3) void maxpool_kernel(float* __restrict__ ws) {
  int s = blockIdx.x;            // 0..3
  int np_ = blockIdx.y, b = blockIdx.z;
  int pi = s >> 1, qi = s & 1;
  int lane = threadIdx.x;        // 64, single wave
  int rsel = lane & 15, quad = lane >> 4;

  const short* Ab = (const short*)(ws + OFF_CPB)
                  + ((size_t)b * Lc + pi * 64 + rsel) * KP + quad * 8;
  const short* Bb = (const short*)(ws + OFF_CHB)
                  + ((size_t)b * Lc + qi * 64 + rsel) * KP + quad * 8;
  const float* w2k = ws + OFF_W2K + (size_t)np_ * KP + quad * 8;

  float4v acc[4][4];
  float4v zf = {0.f, 0.f, 0.f, 0.f};
#pragma unroll
  for (int i = 0; i < 4; i++)
#pragma unroll
    for (int j = 0; j < 4; j++) acc[i][j] = zf;

#pragma unroll
  for (int st = 0; st < 7; st++) {
    int k0 = st * 32;
    float4v w0 = *(const float4v*)(w2k + k0);
    float4v w1 = *(const float4v*)(w2k + k0 + 4);
    short8v bf4[4], af[4];
#pragma unroll
    for (int t = 0; t < 4; t++)
      bf4[t] = *(const short8v*)(Bb + (size_t)t * 16 * KP + k0);
#pragma unroll
    for (int t = 0; t < 4; t++) {
      short8v ar = *(const short8v*)(Ab + (size_t)t * 16 * KP + k0);
      af[t] = weight8(ar, w0, w1);
    }
#pragma unroll
    for (int i = 0; i < 4; i++)
#pragma unroll
      for (int j = 0; j < 4; j++)
        acc[i][j] = __builtin_amdgcn_mfma_f32_16x16x32_bf16(af[i], bf4[j], acc[i][j], 0, 0, 0);
  }

  // epilogue: v = acc / max(nwp*nwh, eps); masked max/mean partials, both axes
  const float* nwp = ws + OFF_NWP + ((size_t)b * NPc + np_) * Lc + pi * 64;
  const float* nwh = ws + OFF_NWH + ((size_t)b * NPc + np_) * Lc + qi * 64;
  const float* maskP = ws + OFF_MASKPF + b * Lc + pi * 64;
  const float* maskH = ws + OFF_MASKHF + b * Lc + qi * 64;
  float nhv[4], mhv[4], cmax[4], csum[4];
#pragma unroll
  for (int tj = 0; tj < 4; tj++) {
    int q = tj * 16 + rsel;
    nhv[tj] = nwh[q];
    mhv[tj] = maskH[q];
    cmax[tj] = NEGF;
    csum[tj] = 0.f;
  }
  size_t rbase = (((size_t)qi * Bc + b) * NPc + np_) * Lc + pi * 64;
  size_t cbase = (((size_t)pi * Bc + b) * NPc + np_) * Lc + qi * 64;
#pragma unroll
  for (int ti = 0; ti < 4; ti++) {
#pragma unroll
    for (int r = 0; r < 4; r++) {
      int p = ti * 16 + quad * 4 + r;
      float npv = nwp[p], mpv = maskP[p];
      float rm = NEGF, rs = 0.f;
#pragma unroll
      for (int tj = 0; tj < 4; tj++) {
        float v = acc[ti][tj][r] * __builtin_amdgcn_rcpf(fmaxf(npv * nhv[tj], EPSF));
        if (mhv[tj] > 0.f) rm = fmaxf(rm, v);
        rs += v * mhv[tj];
        if (mpv > 0.f) cmax[tj] = fmaxf(cmax[tj], v);
        csum[tj] += v * mpv;
      }
#pragma unroll
      for (int o = 1; o <= 8; o <<= 1) {
        rm = fmaxf(rm, __shfl_xor(rm, o));
        rs += __shfl_xor(rs, o);
      }
      if (rsel == 0) {
        ws[OFF_RPMAX + rbase + p] = rm;
        ws[OFF_RPSUM + rbase + p] = rs;
      }
    }
  }
#pragma unroll
  for (int tj = 0; tj < 4; tj++) {
#pragma unroll
    for (int o = 16; o <= 32; o <<= 1) {
      cmax[tj] = fmaxf(cmax[tj], __shfl_xor(cmax[tj], o));
      csum[tj] += __shfl_xor(csum[tj], o);
    }
  }
  if (quad == 0) {
#pragma unroll
    for (int tj = 0; tj < 4; tj++) {
      int q = tj * 16 + rsel;
      ws[OFF_CPMAX + cbase + q] = cmax[tj];
      ws[OFF_CPSUM + cbase + q] = csum[tj];
    }
  }
}

// ---------------- mpm epilogue: lane-per-channel, 2 rows/block, + mpfin ------
__global__ __launch_bounds__(64) void mpm_kernel(float* __restrict__ ws,
                                                 void* __restrict__ out) {
  int bid = blockIdx.x;           // 2*32*64 = 4096
  int side = bid >> 11;
  int b = (bid >> 6) & 31;
  int l0 = (bid & 63) * 2;
  int c = threadIdx.x;  // 64: lane = channel
  int isb = ws[OFF_FLAG] > 0.5f;
  __shared__ float v1s[2][Hc], v2l[Hc], v2a[2][Hc], v2m[2][Hc];
  const float* v1 = ws + (side ? OFF_CHM : OFF_CPM) + ((size_t)b * Lc + l0) * Hc;
  const float* vlast = ws + (side ? OFF_LASTP : OFF_LASTH) + (size_t)b * Hc;
  const float* va = ws + (side ? OFF_AMEANP : OFF_AMEANH) + ((size_t)b * Lc + l0) * Hc;
  const float* vm = ws + (side ? OFF_AMAXP : OFF_AMAXH) + ((size_t)b * Lc + l0) * Hc;
  for (int h = c; h < Hc; h += 64) {
    v1s[0][h] = v1[h];
    v1s[1][h] = v1[h + Hc];
    v2l[h] = vlast[h];
    v2a[0][h] = va[h];
    v2a[1][h] = va[h + Hc];
    v2m[0][h] = vm[h];
    v2m[1][h] = vm[h + Hc];
  }
  // fused mpfin: lanes 0..19 finalize maxpool channels for np=c, both rows
  if (c < NPc) {
    size_t PMX = side ? OFF_CPMAX : OFF_RPMAX;
    size_t PSM = side ? OFF_CPSUM : OFF_RPSUM;
    float len = ws[(side ? OFF_LENP : OFF_LENH) + b];
#pragma unroll
    for (int l = 0; l < 2; l++) {
      size_t i0 = (((size_t)0 * Bc + b) * NPc + c) * Lc + l0 + l;
      size_t i1 = (((size_t)1 * Bc + b) * NPc + c) * Lc + l0 + l;
      float m = fmaxf(ws[PMX + i0], ws[PMX + i1]);
      float sum = ws[PSM + i0] + ws[PSM + i1];
      float mk = ws[(side ? OFF_MASKHF : OFF_MASKPF) + b * Lc + l0 + l];
      size_t orow = (size_t)side * Bc * Lc * NCHc + ((size_t)b * Lc + l0 + l) * NCHc;
      storef(out, orow + 23 + c, mk * m, isb);
      storef(out, orow + 43 + c, mk * sum / fmaxf(mk * len, EPSF), isb);
    }
  }
  __syncthreads();
  int v2i = (c < 20) ? 0 : (c < 40) ? 1 : (c < 60) ? 2 : (c - 60);
  if (v2i > 2) v2i = 2;
  const float* y0 = (v2i == 0) ? v2l : (v2i == 1) ? v2a[0] : v2m[0];
  const float* y1 = (v2i == 0) ? v2l : (v2i == 1) ? v2a[1] : v2m[1];
  const float* wt = ws + OFF_WT + c;
  float sd0 = 0.f, sa0 = 0.f, sb0 = 0.f;
  float sd1 = 0.f, sa1 = 0.f, sb1 = 0.f;
#pragma unroll 4
  for (int h = 0; h < Hc; h++) {
    float wq = wt[(size_t)h * 64];
    float x0 = v1s[0][h], yv0 = y0[h];
    float t0 = wq * x0;
    sd0 += t0 * yv0; sa0 += t0 * x0; sb0 += wq * yv0 * yv0;
    float x1 = v1s[1][h], yv1 = y1[h];
    float t1 = wq * x1;
    sd1 += t1 * yv1; sa1 += t1 * x1; sb1 += wq * yv1 * yv1;
  }
  float mm0 = sd0 / fmaxf(sqrtf(sa0) * sqrtf(sb0), EPSF);
  float mm1 = sd1 / fmaxf(sqrtf(sa1) * sqrtf(sb1), EPSF);
  int ch;
  if (c < 20) ch = 3 + c;
  else if (c < 40) ch = 64 + (c - 20);
  else if (c < 60) ch = 85 + (c - 40);
  else if (c == 60) ch = 2;
  else if (c == 61) ch = 63;
  else if (c == 62) ch = 84;
  else ch = -1;
  if (ch >= 0) {
    size_t orow = ((size_t)side * Bc * Lc + (size_t)b * Lc + l0) * NCHc;
    storef(out, orow + ch, mm0, isb);
    storef(out, orow + NCHc + ch, mm1, isb);
  }
}

extern "C" void kernel_launch(void* const* d_in, const int* in_sizes, int n_in,
                              void* d_out, int out_size, void* d_ws, size_t ws_size,
                              hipStream_t stream) {
  const void* ctx_p = d_in[0];
  const void* mask_p = d_in[1];
  const void* ctx_h = d_in[2];
  const void* mask_h = d_in[3];
  const void* w_full = d_in[4];
  const void* w_mp = d_in[5];
  const void* w_att = d_in[6];
  const void* w_maxatt = d_in[7];
  float* ws = (float*)d_ws;

  convert_kernel<<<178, 256, 0, stream>>>(ctx_p, mask_p, ctx_h, mask_h,
                                          w_full, w_mp, w_att, w_maxatt, ws);
  prep_kernel<<<2 * Bc * Lc, 64, 0, stream>>>(ctx_p, ctx_h, ws);
  cos_kernel<<<Bc * Lc, 128, 0, stream>>>(ws);
  att_kernel<<<dim3(Lc / 4, Bc, 2), 256, 0, stream>>>(ws, d_out);
  maxpool_kernel<<<dim3(4, NPc, Bc), 64, 0, stream>>>(ws);
  mpm_kernel<<<2 * Bc * 64, 64, 0, stream>>>(ws, d_out);
}

// Round 7
// 188.660 us; speedup vs baseline: 1.5874x; 1.1214x over previous
//
#include <hip/hip_runtime.h>
#include <hip/hip_bf16.h>

// BiMPM matching, B=32, L=128, H=200, NP=20.
// Input/output dtype (bf16 vs f32) detected at runtime from mask_p[0] bit
// pattern. All compute in f32 via ws. Both the maxpool GEMM and the cos GEMM
// run on bf16 MFMA with fragments loaded directly from global (no LDS);
// cos is exact (masked bf16 inputs are exactly representable), maxpool has
// one w^2*x bf16 round (|dcos| <= 2^-9). 5 launches:
// convert(+lastlen), prep, maxpool(+cos), att(+ch01), mpm(+mpfin).
// Output: mv_p (32,128,105), mv_h same.

#define EPSF 1e-8f
#define NEGF -1e7f

constexpr int Bc = 32, Lc = 128, Hc = 200, NPc = 20, NCHc = 105;
constexpr int KP = 224;    // padded K (7 x 32)
constexpr size_t SLH = (size_t)Bc * Lc * Hc;   // 819200
constexpr size_t SLL = (size_t)Bc * Lc * Lc;   // 524288

// workspace layout (floats)
constexpr size_t OFF_CPM    = 0;
constexpr size_t OFF_CHM    = OFF_CPM + SLH;
constexpr size_t OFF_CHMT   = OFF_CHM + SLH;       // (unused after R7)
constexpr size_t OFF_COS    = OFF_CHMT + SLH;      // [b][p][q]
constexpr size_t OFF_COST   = OFF_COS + SLL;       // [b][q][p]
constexpr size_t OFF_AMEANH = OFF_COST + SLL;      // (b,Lp,H)
constexpr size_t OFF_AMAXH  = OFF_AMEANH + SLH;
constexpr size_t OFF_AMEANP = OFF_AMAXH + SLH;     // (b,Lh,H)
constexpr size_t OFF_AMAXP  = OFF_AMEANP + SLH;
constexpr size_t OFF_NORMP  = OFF_AMAXP + SLH;
constexpr size_t OFF_NORMH  = OFF_NORMP + (size_t)Bc * Lc;
constexpr size_t OFF_LENP   = OFF_NORMH + (size_t)Bc * Lc;
constexpr size_t OFF_LENH   = OFF_LENP + Bc;
constexpr size_t OFF_LASTP  = OFF_LENH + Bc;
constexpr size_t OFF_LASTH  = OFF_LASTP + (size_t)Bc * Hc;
constexpr size_t OFF_NWP    = OFF_LASTH + (size_t)Bc * Hc;  // [b][np][l]
constexpr size_t OFF_NWH    = OFF_NWP + (size_t)Bc * NPc * Lc;
constexpr size_t OFF_MASKPF = OFF_NWH + (size_t)Bc * NPc * Lc;
constexpr size_t OFF_MASKHF = OFF_MASKPF + (size_t)Bc * Lc;
constexpr size_t OFF_WFULL  = OFF_MASKHF + (size_t)Bc * Lc;
constexpr size_t OFF_WMP    = OFF_WFULL + (size_t)NPc * Hc;
constexpr size_t OFF_WATT   = OFF_WMP + (size_t)NPc * Hc;
constexpr size_t OFF_WMATT  = OFF_WATT + (size_t)NPc * Hc;
constexpr size_t OFF_FLAG   = OFF_WMATT + (size_t)NPc * Hc;
constexpr size_t OFF_WT     = OFF_FLAG + 64;                // [c][h] squared-weights, 64 x Hc
constexpr size_t OFF_RPMAX  = OFF_WT + (size_t)Hc * 64;     // [qi][b][np][p]
constexpr size_t OFF_RPSUM  = OFF_RPMAX + 2 * (size_t)Bc * NPc * Lc;
constexpr size_t OFF_CPMAX  = OFF_RPSUM + 2 * (size_t)Bc * NPc * Lc;  // [pi][b][np][q]
constexpr size_t OFF_CPSUM  = OFF_CPMAX + 2 * (size_t)Bc * NPc * Lc;
constexpr size_t OFF_CHB    = OFF_CPSUM + 2 * (size_t)Bc * NPc * Lc;  // bf16 [b][l][KP]
constexpr size_t OFF_CPB    = OFF_CHB + ((size_t)Bc * Lc * KP) / 2;   // bf16 [b][l][KP]
constexpr size_t OFF_W2K    = OFF_CPB + ((size_t)Bc * Lc * KP) / 2;   // f32 [np][KP]
constexpr size_t WS_FLOATS  = OFF_W2K + (size_t)NPc * KP;   // ~8.6M floats (~34.4 MB)

typedef __attribute__((ext_vector_type(8))) short short8v;
typedef __attribute__((ext_vector_type(4))) short short4v;
typedef __attribute__((ext_vector_type(4))) float float4v;

__device__ __forceinline__ float loadf(const void* p, size_t i, int isb) {
  if (isb) return __bfloat162float(((const __hip_bfloat16*)p)[i]);
  return ((const float*)p)[i];
}

__device__ __forceinline__ void storef(void* out, size_t i, float v, int isb) {
  if (isb) ((__hip_bfloat16*)out)[i] = __float2bfloat16(v);
  else ((float*)out)[i] = v;
}

__device__ __forceinline__ short b2s(float f) {
  __hip_bfloat16 h = __float2bfloat16(f);
  union { __hip_bfloat16 b; short s; } u;
  u.b = h;
  return u.s;
}

// unpack bf16 lane, scale by w (f32), repack to bf16
__device__ __forceinline__ short8v weight8(short8v a, float4v w0, float4v w1) {
  short8v r;
#pragma unroll
  for (int e = 0; e < 8; e++) {
    union { unsigned u; float f; } c;
    c.u = ((unsigned)(unsigned short)a[e]) << 16;
    float w = (e < 4) ? w0[e] : w1[e - 4];
    r[e] = b2s(c.f * w);
  }
  return r;
}

// ---------------- convert: dtype detect, small-input f32 copies, tables,
// ---------------- plus fused lastlen (lengths + last-token vectors) ----------
__global__ void convert_kernel(const void* cp_, const void* mp, const void* ch_,
                               const void* mh, const void* wf, const void* wmp,
                               const void* watt, const void* wma,
                               float* __restrict__ ws) {
  int isb = (((const unsigned short*)mp)[0] == 0x3F80u) ? 1 : 0;
  int bid = blockIdx.x;
  const int n0 = Bc * Lc;          // 4096
  const int nw = NPc * Hc;         // 4000
  if (bid >= 162) {
    // lastlen: 16 blocks x 4 (side,b) pairs, one wave per pair
    int t = threadIdx.x;
    int idx = (bid - 162) * 4 + (t >> 6);   // 0..63
    int side = idx >> 5, b = idx & 31;
    int lane = t & 63;
    const void* mask = side ? mh : mp;
    const void* ctx = side ? ch_ : cp_;
    float s = 0.f;
    for (int l = lane; l < Lc; l += 64) s += loadf(mask, b * Lc + l, isb);
    for (int o = 32; o > 0; o >>= 1) s += __shfl_xor(s, o);
    if (lane == 0) ws[(side ? OFF_LENH : OFF_LENP) + b] = s;
    int lidx = (int)(s + 0.5f) - 1;
    if (lidx < 0) lidx = 0;
    float mk = loadf(mask, b * Lc + lidx, isb);
    float* lastv = ws + (side ? OFF_LASTH : OFF_LASTP) + (size_t)b * Hc;
    for (int h = lane; h < Hc; h += 64)
      lastv[h] = loadf(ctx, ((size_t)b * Lc + lidx) * Hc + h, isb) * mk;
    return;
  }
  int g = bid * 256 + threadIdx.x;
  if (g == 0) ws[OFF_FLAG] = (float)isb;
  if (g < n0) {
    ws[OFF_MASKPF + g] = loadf(mp, g, isb);
  } else if (g < 2 * n0) {
    ws[OFF_MASKHF + (g - n0)] = loadf(mh, g - n0, isb);
  } else if (g < 2 * n0 + 4 * nw) {
    int r = g - 2 * n0;
    int seg = r / nw, off = r % nw;
    if (seg == 0) ws[OFF_WFULL + off] = loadf(wf, off, isb);
    else if (seg == 1) ws[OFF_WMP + off] = loadf(wmp, off, isb);
    else if (seg == 2) ws[OFF_WATT + off] = loadf(watt, off, isb);
    else ws[OFF_WMATT + off] = loadf(wma, off, isb);
  } else if (g < 2 * n0 + 4 * nw + 64 * Hc) {
    // wT table, layout [c][h]: per-channel squared weight rows
    int r = g - (2 * n0 + 4 * nw);
    int c = r / Hc, h = r % Hc;
    float w = 1.0f;
    if (c < 20) w = loadf(wf, (size_t)c * Hc + h, isb);
    else if (c < 40) w = loadf(watt, (size_t)(c - 20) * Hc + h, isb);
    else if (c < 60) w = loadf(wma, (size_t)(c - 40) * Hc + h, isb);
    ws[OFF_WT + r] = w * w;
  } else if (g < 2 * n0 + 4 * nw + 64 * Hc + NPc * KP) {
    int r = g - (2 * n0 + 4 * nw + 64 * Hc);
    int np_ = r / KP, k = r % KP;
    float w = (k < Hc) ? loadf(wmp, (size_t)np_ * Hc + k, isb) : 0.f;
    ws[OFF_W2K + r] = w * w;
  }
}

// ---------------- prep: masked copies, cpb/chb(bf16), norms, w-norms ---------
__global__ void prep_kernel(const void* __restrict__ ctx_p,
                            const void* __restrict__ ctx_h,
                            float* __restrict__ ws) {
  int bid = blockIdx.x;
  int side = bid >> 12;
  int bl = bid & 4095;
  int b = bl >> 7, l = bl & 127;
  int lane = threadIdx.x;      // 64
  int isb = ws[OFF_FLAG] > 0.5f;
  const void* ctx = side ? ctx_h : ctx_p;
  const float* mask = ws + (side ? OFF_MASKHF : OFF_MASKPF);
  float mk = mask[b * Lc + l];
  size_t rowbase = ((size_t)b * Lc + l) * Hc;
  float* cm = ws + (side ? OFF_CHM : OFF_CPM) + rowbase;
  __hip_bfloat16* cb16 = (__hip_bfloat16*)(ws + (side ? OFF_CHB : OFF_CPB));
  size_t cb = ((size_t)b * Lc + l) * KP;

  float v[4];
  float ss = 0.f;
  for (int i = 0; i < 4; i++) {
    int h = lane + 64 * i;
    float x = 0.f;
    if (h < Hc) {
      x = loadf(ctx, rowbase + h, isb) * mk;
      cm[h] = x;
      cb16[cb + h] = __float2bfloat16(x);
    } else if (h < KP) {
      cb16[cb + h] = __float2bfloat16(0.f);
    }
    v[i] = x;
    ss += x * x;
  }
  for (int o = 32; o > 0; o >>= 1) ss += __shfl_xor(ss, o);
  if (lane == 0) ws[(side ? OFF_NORMH : OFF_NORMP) + b * Lc + l] = sqrtf(ss);

  const float* wmpf = ws + OFF_WMP;
  float* nw = ws + (side ? OFF_NWH : OFF_NWP) + (size_t)b * NPc * Lc;
  for (int np_ = 0; np_ < NPc; np_++) {
    float s = 0.f;
    for (int i = 0; i < 4; i++) {
      int h = lane + 64 * i;
      if (h < Hc) {
        float w = wmpf[np_ * Hc + h];
        float wx = w * v[i];
        s += wx * wx;
      }
    }
    for (int o = 32; o > 0; o >>= 1) s += __shfl_xor(s, o);
    if (lane == 0) nw[np_ * Lc + l] = sqrtf(s);
  }
}

// ---------------- maxpool + cos: 64x64x224 bf16-MFMA, no LDS, frag-direct ----
// blockIdx.y in [0,NPc) -> maxpool perspective; == NPc -> cos mode (exact).
__global__ __launch_bounds__(64, 3) void maxpool_kernel(float* __restrict__ ws) {
  int s = blockIdx.x;            // 0..3
  int np_ = blockIdx.y, b = blockIdx.z;
  int pi = s >> 1, qi = s & 1;
  int cosmode = (np_ == NPc);
  int lane = threadIdx.x;        // 64, single wave
  int rsel = lane & 15, quad = lane >> 4;

  const short* Ab = (const short*)(ws + OFF_CPB)
                  + ((size_t)b * Lc + pi * 64 + rsel) * KP + quad * 8;
  const short* Bb = (const short*)(ws + OFF_CHB)
                  + ((size_t)b * Lc + qi * 64 + rsel) * KP + quad * 8;
  const float* w2k = ws + OFF_W2K + (size_t)(cosmode ? 0 : np_) * KP + quad * 8;

  float4v acc[4][4];
  float4v zf = {0.f, 0.f, 0.f, 0.f};
#pragma unroll
  for (int i = 0; i < 4; i++)
#pragma unroll
    for (int j = 0; j < 4; j++) acc[i][j] = zf;

#pragma unroll
  for (int st = 0; st < 7; st++) {
    int k0 = st * 32;
    short8v bf4[4], af[4];
#pragma unroll
    for (int t = 0; t < 4; t++)
      bf4[t] = *(const short8v*)(Bb + (size_t)t * 16 * KP + k0);
    if (cosmode) {
#pragma unroll
      for (int t = 0; t < 4; t++)
        af[t] = *(const short8v*)(Ab + (size_t)t * 16 * KP + k0);
    } else {
      float4v w0 = *(const float4v*)(w2k + k0);
      float4v w1 = *(const float4v*)(w2k + k0 + 4);
#pragma unroll
      for (int t = 0; t < 4; t++) {
        short8v ar = *(const short8v*)(Ab + (size_t)t * 16 * KP + k0);
        af[t] = weight8(ar, w0, w1);
      }
    }
#pragma unroll
    for (int i = 0; i < 4; i++)
#pragma unroll
      for (int j = 0; j < 4; j++)
        acc[i][j] = __builtin_amdgcn_mfma_f32_16x16x32_bf16(af[i], bf4[j], acc[i][j], 0, 0, 0);
  }

  if (cosmode) {
    // cos epilogue: v = acc / max(normp*normh, eps); write cos + cosT tiles
    const float* npn = ws + OFF_NORMP + b * Lc + pi * 64;
    const float* nhn = ws + OFF_NORMH + b * Lc + qi * 64;
    float nh4[4];
#pragma unroll
    for (int tj = 0; tj < 4; tj++) nh4[tj] = nhn[tj * 16 + rsel];
    float* cosp = ws + OFF_COS + (size_t)b * Lc * Lc;
    float* cost = ws + OFF_COST + (size_t)b * Lc * Lc;
#pragma unroll
    for (int ti = 0; ti < 4; ti++) {
#pragma unroll
      for (int r = 0; r < 4; r++) {
        int prow = pi * 64 + ti * 16 + quad * 4 + r;
        float npv = npn[ti * 16 + quad * 4 + r];
#pragma unroll
        for (int tj = 0; tj < 4; tj++) {
          int qcol = qi * 64 + tj * 16 + rsel;
          float v = acc[ti][tj][r] * __builtin_amdgcn_rcpf(fmaxf(npv * nh4[tj], EPSF));
          cosp[(size_t)prow * Lc + qcol] = v;
          cost[(size_t)qcol * Lc + prow] = v;
        }
      }
    }
    return;
  }

  // maxpool epilogue: v = acc / max(nwp*nwh, eps); masked max/mean partials
  const float* nwp = ws + OFF_NWP + ((size_t)b * NPc + np_) * Lc + pi * 64;
  const float* nwh = ws + OFF_NWH + ((size_t)b * NPc + np_) * Lc + qi * 64;
  const float* maskP = ws + OFF_MASKPF + b * Lc + pi * 64;
  const float* maskH = ws + OFF_MASKHF + b * Lc + qi * 64;
  float nhv[4], mhv[4], cmax[4], csum[4];
#pragma unroll
  for (int tj = 0; tj < 4; tj++) {
    int q = tj * 16 + rsel;
    nhv[tj] = nwh[q];
    mhv[tj] = maskH[q];
    cmax[tj] = NEGF;
    csum[tj] = 0.f;
  }
  size_t rbase = (((size_t)qi * Bc + b) * NPc + np_) * Lc + pi * 64;
  size_t cbase = (((size_t)pi * Bc + b) * NPc + np_) * Lc + qi * 64;
#pragma unroll
  for (int ti = 0; ti < 4; ti++) {
#pragma unroll
    for (int r = 0; r < 4; r++) {
      int p = ti * 16 + quad * 4 + r;
      float npv = nwp[p], mpv = maskP[p];
      float rm = NEGF, rs = 0.f;
#pragma unroll
      for (int tj = 0; tj < 4; tj++) {
        float v = acc[ti][tj][r] * __builtin_amdgcn_rcpf(fmaxf(npv * nhv[tj], EPSF));
        if (mhv[tj] > 0.f) rm = fmaxf(rm, v);
        rs += v * mhv[tj];
        if (mpv > 0.f) cmax[tj] = fmaxf(cmax[tj], v);
        csum[tj] += v * mpv;
      }
#pragma unroll
      for (int o = 1; o <= 8; o <<= 1) {
        rm = fmaxf(rm, __shfl_xor(rm, o));
        rs += __shfl_xor(rs, o);
      }
      if (rsel == 0) {
        ws[OFF_RPMAX + rbase + p] = rm;
        ws[OFF_RPSUM + rbase + p] = rs;
      }
    }
  }
#pragma unroll
  for (int tj = 0; tj < 4; tj++) {
#pragma unroll
    for (int o = 16; o <= 32; o <<= 1) {
      cmax[tj] = fmaxf(cmax[tj], __shfl_xor(cmax[tj], o));
      csum[tj] += __shfl_xor(csum[tj], o);
    }
  }
  if (quad == 0) {
#pragma unroll
    for (int tj = 0; tj < 4; tj++) {
      int q = tj * 16 + rsel;
      ws[OFF_CPMAX + cbase + q] = cmax[tj];
      ws[OFF_CPSUM + cbase + q] = csum[tj];
    }
  }
}

// ---------------- fused attentive mean+max, 4 rows/block, + ch0/1 ------------
__global__ __launch_bounds__(256) void att_kernel(float* __restrict__ ws,
                                                  void* __restrict__ out) {
  int side = blockIdx.z;
  int b = blockIdx.y;
  int r0 = blockIdx.x * 4;
  int t = threadIdx.x;  // 256
  int isb = ws[OFF_FLAG] > 0.5f;
  const float* cosrows = ws + (side ? OFF_COST : OFF_COS) + ((size_t)b * Lc + r0) * Lc;
  const float* vsrc = ws + (side ? OFF_CPM : OFF_CHM) + (size_t)b * Lc * Hc;
  const float* maskLoop = ws + (side ? OFF_MASKPF : OFF_MASKHF) + b * Lc;
  const float* maskRow = ws + (side ? OFF_MASKHF : OFF_MASKPF) + b * Lc;
  float lenOther = ws[(side ? OFF_LENP : OFF_LENH) + b];
  float* amean = ws + (side ? OFF_AMEANP : OFF_AMEANH) + ((size_t)b * Lc + r0) * Hc;
  float* amax = ws + (side ? OFF_AMAXP : OFF_AMAXH) + ((size_t)b * Lc + r0) * Hc;

  __shared__ float crow[4][Lc];
  __shared__ float mneg[Lc];
  __shared__ float dens[4];
  for (int i = t; i < 4 * Lc; i += 256) crow[i >> 7][i & 127] = cosrows[i];
  if (t < Lc) mneg[t] = (maskLoop[t] > 0.f) ? 0.f : -1e30f;
  __syncthreads();

  // per-row stats: wave w handles row r0+w  -> denom + out channels 0,1
  int wv = t >> 6, lane = t & 63;
  {
    float x1 = crow[wv][lane], x2 = crow[wv][lane + 64];
    float sv = x1 + x2;
    float mv = fmaxf(x1 + mneg[lane], x2 + mneg[lane + 64]);
    for (int o = 32; o > 0; o >>= 1) {
      sv += __shfl_xor(sv, o);
      mv = fmaxf(mv, __shfl_xor(mv, o));
    }
    if (lane == 0) {
      dens[wv] = sv;
      float mr = maskRow[r0 + wv];
      size_t orow = (size_t)side * Bc * Lc * NCHc + ((size_t)b * Lc + r0 + wv) * NCHc;
      storef(out, orow + 0, mr * mv, isb);
      storef(out, orow + 1, mr * sv / fmaxf(mr * lenOther, EPSF), isb);
    }
  }
  __syncthreads();

  if (t < Hc) {
    float s0 = 0.f, s1 = 0.f, s2 = 0.f, s3 = 0.f;
    float m0 = NEGF, m1 = NEGF, m2 = NEGF, m3 = NEGF;
    const float* vb = vsrc + t;
#pragma unroll 4
    for (int q = 0; q < Lc; q++) {
      float pr = vb[(size_t)q * Hc];
      float mn = mneg[q];
      float v0 = crow[0][q] * pr; s0 += v0; m0 = fmaxf(m0, v0 + mn);
      float v1 = crow[1][q] * pr; s1 += v1; m1 = fmaxf(m1, v1 + mn);
      float v2 = crow[2][q] * pr; s2 += v2; m2 = fmaxf(m2, v2 + mn);
      float v3 = crow[3][q] * pr; s3 += v3; m3 = fmaxf(m3, v3 + mn);
    }
    amean[0 * Hc + t] = s0 / fmaxf(dens[0], EPSF);
    amean[1 * Hc + t] = s1 / fmaxf(dens[1], EPSF);
    amean[2 * Hc + t] = s2 / fmaxf(dens[2], EPSF);
    amean[3 * Hc + t] = s3 / fmaxf(dens[3], EPSF);
    amax[0 * Hc + t] = maskRow[r0 + 0] * m0;
    amax[1 * Hc + t] = maskRow[r0 + 1] * m1;
    amax[2 * Hc + t] = maskRow[r0 + 2] * m2;
    amax[3 * Hc + t] = maskRow[r0 + 3] * m3;
  }
}

// ---------------- mpm epilogue: lane-per-channel, 2 rows/block, + mpfin ------
__global__ __launch_bounds__(64) void mpm_kernel(float* __restrict__ ws,
                                                 void* __restrict__ out) {
  int bid = blockIdx.x;           // 2*32*64 = 4096
  int side = bid >> 11;
  int b = (bid >> 6) & 31;
  int l0 = (bid & 63) * 2;
  int c = threadIdx.x;  // 64: lane = channel
  int isb = ws[OFF_FLAG] > 0.5f;
  __shared__ float v1s[2][Hc], v2l[Hc], v2a[2][Hc], v2m[2][Hc];
  const float* v1 = ws + (side ? OFF_CHM : OFF_CPM) + ((size_t)b * Lc + l0) * Hc;
  const float* vlast = ws + (side ? OFF_LASTP : OFF_LASTH) + (size_t)b * Hc;
  const float* va = ws + (side ? OFF_AMEANP : OFF_AMEANH) + ((size_t)b * Lc + l0) * Hc;
  const float* vm = ws + (side ? OFF_AMAXP : OFF_AMAXH) + ((size_t)b * Lc + l0) * Hc;
  for (int h = c; h < Hc; h += 64) {
    v1s[0][h] = v1[h];
    v1s[1][h] = v1[h + Hc];
    v2l[h] = vlast[h];
    v2a[0][h] = va[h];
    v2a[1][h] = va[h + Hc];
    v2m[0][h] = vm[h];
    v2m[1][h] = vm[h + Hc];
  }
  // fused mpfin: lanes 0..19 finalize maxpool channels for np=c, both rows
  if (c < NPc) {
    size_t PMX = side ? OFF_CPMAX : OFF_RPMAX;
    size_t PSM = side ? OFF_CPSUM : OFF_RPSUM;
    float len = ws[(side ? OFF_LENP : OFF_LENH) + b];
#pragma unroll
    for (int l = 0; l < 2; l++) {
      size_t i0 = (((size_t)0 * Bc + b) * NPc + c) * Lc + l0 + l;
      size_t i1 = (((size_t)1 * Bc + b) * NPc + c) * Lc + l0 + l;
      float m = fmaxf(ws[PMX + i0], ws[PMX + i1]);
      float sum = ws[PSM + i0] + ws[PSM + i1];
      float mk = ws[(side ? OFF_MASKHF : OFF_MASKPF) + b * Lc + l0 + l];
      size_t orow = (size_t)side * Bc * Lc * NCHc + ((size_t)b * Lc + l0 + l) * NCHc;
      storef(out, orow + 23 + c, mk * m, isb);
      storef(out, orow + 43 + c, mk * sum / fmaxf(mk * len, EPSF), isb);
    }
  }
  __syncthreads();
  int v2i = (c < 20) ? 0 : (c < 40) ? 1 : (c < 60) ? 2 : (c - 60);
  if (v2i > 2) v2i = 2;
  const float* y0 = (v2i == 0) ? v2l : (v2i == 1) ? v2a[0] : v2m[0];
  const float* y1 = (v2i == 0) ? v2l : (v2i == 1) ? v2a[1] : v2m[1];
  const float* wt = ws + OFF_WT + (size_t)c * Hc;   // per-channel row, [c][h]
  float sd0 = 0.f, sa0 = 0.f, sb0 = 0.f;
  float sd1 = 0.f, sa1 = 0.f, sb1 = 0.f;
#pragma unroll 2
  for (int h4 = 0; h4 < Hc / 4; h4++) {
    float4 wq = *(const float4*)(wt + h4 * 4);
    float4 x0 = *(const float4*)&v1s[0][h4 * 4];
    float4 x1 = *(const float4*)&v1s[1][h4 * 4];
    float4 ya = *(const float4*)&y0[h4 * 4];
    float4 yb = *(const float4*)&y1[h4 * 4];
    float t0;
    t0 = wq.x * x0.x; sd0 += t0 * ya.x; sa0 += t0 * x0.x; sb0 += wq.x * ya.x * ya.x;
    t0 = wq.y * x0.y; sd0 += t0 * ya.y; sa0 += t0 * x0.y; sb0 += wq.y * ya.y * ya.y;
    t0 = wq.z * x0.z; sd0 += t0 * ya.z; sa0 += t0 * x0.z; sb0 += wq.z * ya.z * ya.z;
    t0 = wq.w * x0.w; sd0 += t0 * ya.w; sa0 += t0 * x0.w; sb0 += wq.w * ya.w * ya.w;
    t0 = wq.x * x1.x; sd1 += t0 * yb.x; sa1 += t0 * x1.x; sb1 += wq.x * yb.x * yb.x;
    t0 = wq.y * x1.y; sd1 += t0 * yb.y; sa1 += t0 * x1.y; sb1 += wq.y * yb.y * yb.y;
    t0 = wq.z * x1.z; sd1 += t0 * yb.z; sa1 += t0 * x1.z; sb1 += wq.z * yb.z * yb.z;
    t0 = wq.w * x1.w; sd1 += t0 * yb.w; sa1 += t0 * x1.w; sb1 += wq.w * yb.w * yb.w;
  }
  float mm0 = sd0 / fmaxf(sqrtf(sa0) * sqrtf(sb0), EPSF);
  float mm1 = sd1 / fmaxf(sqrtf(sa1) * sqrtf(sb1), EPSF);
  int ch;
  if (c < 20) ch = 3 + c;
  else if (c < 40) ch = 64 + (c - 20);
  else if (c < 60) ch = 85 + (c - 40);
  else if (c == 60) ch = 2;
  else if (c == 61) ch = 63;
  else if (c == 62) ch = 84;
  else ch = -1;
  if (ch >= 0) {
    size_t orow = ((size_t)side * Bc * Lc + (size_t)b * Lc + l0) * NCHc;
    storef(out, orow + ch, mm0, isb);
    storef(out, orow + NCHc + ch, mm1, isb);
  }
}

extern "C" void kernel_launch(void* const* d_in, const int* in_sizes, int n_in,
                              void* d_out, int out_size, void* d_ws, size_t ws_size,
                              hipStream_t stream) {
  const void* ctx_p = d_in[0];
  const void* mask_p = d_in[1];
  const void* ctx_h = d_in[2];
  const void* mask_h = d_in[3];
  const void* w_full = d_in[4];
  const void* w_mp = d_in[5];
  const void* w_att = d_in[6];
  const void* w_maxatt = d_in[7];
  float* ws = (float*)d_ws;

  convert_kernel<<<178, 256, 0, stream>>>(ctx_p, mask_p, ctx_h, mask_h,
                                          w_full, w_mp, w_att, w_maxatt, ws);
  prep_kernel<<<2 * Bc * Lc, 64, 0, stream>>>(ctx_p, ctx_h, ws);
  maxpool_kernel<<<dim3(4, NPc + 1, Bc), 64, 0, stream>>>(ws);
  att_kernel<<<dim3(Lc / 4, Bc, 2), 256, 0, stream>>>(ws, d_out);
  mpm_kernel<<<2 * Bc * 64, 64, 0, stream>>>(ws, d_out);
}

// Round 8
// 167.474 us; speedup vs baseline: 1.7882x; 1.1265x over previous
//
#include <hip/hip_runtime.h>
#include <hip/hip_bf16.h>

// BiMPM matching, B=32, L=128, H=200, NP=20.
// Input/output dtype (bf16 vs f32) detected at runtime from mask_p[0] bit
// pattern. All compute in f32 via ws. Both the maxpool GEMM and the cos GEMM
// run on bf16 MFMA with fragments loaded directly from global (no LDS);
// cos is exact (masked bf16 inputs are exactly representable), maxpool has
// one w^2*x bf16 round (|dcos| <= 2^-9). 3 launches:
// prep(+convert+lastlen), maxpool(+cos), attmpm (att + all output channels).
// Output: mv_p (32,128,105), mv_h same.

#define EPSF 1e-8f
#define NEGF -1e7f

constexpr int Bc = 32, Lc = 128, Hc = 200, NPc = 20, NCHc = 105;
constexpr int KP = 224;    // padded K (7 x 32)
constexpr size_t SLH = (size_t)Bc * Lc * Hc;   // 819200
constexpr size_t SLL = (size_t)Bc * Lc * Lc;   // 524288

// workspace layout (floats)
constexpr size_t OFF_CPM    = 0;
constexpr size_t OFF_CHM    = OFF_CPM + SLH;
constexpr size_t OFF_COS    = OFF_CHM + SLH;       // [b][p][q]
constexpr size_t OFF_COST   = OFF_COS + SLL;       // [b][q][p]
constexpr size_t OFF_NORMP  = OFF_COST + SLL;
constexpr size_t OFF_NORMH  = OFF_NORMP + (size_t)Bc * Lc;
constexpr size_t OFF_LENP   = OFF_NORMH + (size_t)Bc * Lc;
constexpr size_t OFF_LENH   = OFF_LENP + Bc;
constexpr size_t OFF_LASTP  = OFF_LENH + Bc;
constexpr size_t OFF_LASTH  = OFF_LASTP + (size_t)Bc * Hc;
constexpr size_t OFF_NWP    = OFF_LASTH + (size_t)Bc * Hc;  // [b][np][l]
constexpr size_t OFF_NWH    = OFF_NWP + (size_t)Bc * NPc * Lc;
constexpr size_t OFF_MASKPF = OFF_NWH + (size_t)Bc * NPc * Lc;
constexpr size_t OFF_MASKHF = OFF_MASKPF + (size_t)Bc * Lc;
constexpr size_t OFF_FLAG   = OFF_MASKHF + (size_t)Bc * Lc;
constexpr size_t OFF_WT     = OFF_FLAG + 64;                // [c][h] squared weights, 64 x Hc
constexpr size_t OFF_RPMAX  = OFF_WT + (size_t)Hc * 64;     // [qi][b][np][p]
constexpr size_t OFF_RPSUM  = OFF_RPMAX + 2 * (size_t)Bc * NPc * Lc;
constexpr size_t OFF_CPMAX  = OFF_RPSUM + 2 * (size_t)Bc * NPc * Lc;  // [pi][b][np][q]
constexpr size_t OFF_CPSUM  = OFF_CPMAX + 2 * (size_t)Bc * NPc * Lc;
constexpr size_t OFF_CHB    = OFF_CPSUM + 2 * (size_t)Bc * NPc * Lc;  // bf16 [b][l][KP]
constexpr size_t OFF_CPB    = OFF_CHB + ((size_t)Bc * Lc * KP) / 2;   // bf16 [b][l][KP]
constexpr size_t OFF_W2K    = OFF_CPB + ((size_t)Bc * Lc * KP) / 2;   // f32 [np][KP]
constexpr size_t WS_FLOATS  = OFF_W2K + (size_t)NPc * KP;

typedef __attribute__((ext_vector_type(8))) short short8v;
typedef __attribute__((ext_vector_type(4))) float float4v;

__device__ __forceinline__ float loadf(const void* p, size_t i, int isb) {
  if (isb) return __bfloat162float(((const __hip_bfloat16*)p)[i]);
  return ((const float*)p)[i];
}

__device__ __forceinline__ void storef(void* out, size_t i, float v, int isb) {
  if (isb) ((__hip_bfloat16*)out)[i] = __float2bfloat16(v);
  else ((float*)out)[i] = v;
}

__device__ __forceinline__ short b2s(float f) {
  __hip_bfloat16 h = __float2bfloat16(f);
  union { __hip_bfloat16 b; short s; } u;
  u.b = h;
  return u.s;
}

// unpack bf16 lane, scale by w (f32), repack to bf16
__device__ __forceinline__ short8v weight8(short8v a, float4v w0, float4v w1) {
  short8v r;
#pragma unroll
  for (int e = 0; e < 8; e++) {
    union { unsigned u; float f; } c;
    c.u = ((unsigned)(unsigned short)a[e]) << 16;
    float w = (e < 4) ? w0[e] : w1[e - 4];
    r[e] = b2s(c.f * w);
  }
  return r;
}

// ---------------- prep (+convert +lastlen), one launch -----------------------
// blocks [0,2048): 4 waves x 1 row each -> masked copy, bf16 row, norms, w-norms
// blocks [2048,2148): masks f32, wT table, W2K table, FLAG
// blocks [2148,2164): lastlen (lengths + last-token vectors)
__global__ __launch_bounds__(256) void prep_kernel(
    const void* __restrict__ cp_, const void* __restrict__ mp,
    const void* __restrict__ ch_, const void* __restrict__ mh,
    const void* __restrict__ wf, const void* __restrict__ wmp,
    const void* __restrict__ watt, const void* __restrict__ wma,
    float* __restrict__ ws) {
  int isb = (((const unsigned short*)mp)[0] == 0x3F80u) ? 1 : 0;
  int bid = blockIdx.x;
  int t = threadIdx.x;
  const int n0 = Bc * Lc;          // 4096
  if (bid < 2048) {
    int g = bid * 4 + (t >> 6);    // row index 0..8191
    int side = g >> 12;
    int bl = g & 4095;
    int b = bl >> 7, l = bl & 127;
    int lane = t & 63;
    const void* ctx = side ? ch_ : cp_;
    const void* maskin = side ? mh : mp;
    float mk = loadf(maskin, b * Lc + l, isb);
    size_t rowbase = ((size_t)b * Lc + l) * Hc;
    float* cm = ws + (side ? OFF_CHM : OFF_CPM) + rowbase;
    __hip_bfloat16* cb16 = (__hip_bfloat16*)(ws + (side ? OFF_CHB : OFF_CPB));
    size_t cb = ((size_t)b * Lc + l) * KP;

    float v[4];
    float ss = 0.f;
    for (int i = 0; i < 4; i++) {
      int h = lane + 64 * i;
      float x = 0.f;
      if (h < Hc) {
        x = loadf(ctx, rowbase + h, isb) * mk;
        cm[h] = x;
        cb16[cb + h] = __float2bfloat16(x);
      } else if (h < KP) {
        cb16[cb + h] = __float2bfloat16(0.f);
      }
      v[i] = x;
      ss += x * x;
    }
    for (int o = 32; o > 0; o >>= 1) ss += __shfl_xor(ss, o);
    if (lane == 0) ws[(side ? OFF_NORMH : OFF_NORMP) + b * Lc + l] = sqrtf(ss);

    float* nw = ws + (side ? OFF_NWH : OFF_NWP) + (size_t)b * NPc * Lc;
    for (int np_ = 0; np_ < NPc; np_++) {
      float s = 0.f;
      for (int i = 0; i < 4; i++) {
        int h = lane + 64 * i;
        if (h < Hc) {
          float w = loadf(wmp, (size_t)np_ * Hc + h, isb);
          float wx = w * v[i];
          s += wx * wx;
        }
      }
      for (int o = 32; o > 0; o >>= 1) s += __shfl_xor(s, o);
      if (lane == 0) nw[np_ * Lc + l] = sqrtf(s);
    }
    return;
  }
  int cb = bid - 2048;
  if (cb >= 100) {
    // lastlen: 16 blocks x 4 (side,b) pairs, one wave per pair
    int idx = (cb - 100) * 4 + (t >> 6);   // 0..63
    int side = idx >> 5, b = idx & 31;
    int lane = t & 63;
    const void* mask = side ? mh : mp;
    const void* ctx = side ? ch_ : cp_;
    float s = 0.f;
    for (int l = lane; l < Lc; l += 64) s += loadf(mask, b * Lc + l, isb);
    for (int o = 32; o > 0; o >>= 1) s += __shfl_xor(s, o);
    if (lane == 0) ws[(side ? OFF_LENH : OFF_LENP) + b] = s;
    int lidx = (int)(s + 0.5f) - 1;
    if (lidx < 0) lidx = 0;
    float mk = loadf(mask, b * Lc + lidx, isb);
    float* lastv = ws + (side ? OFF_LASTH : OFF_LASTP) + (size_t)b * Hc;
    for (int h = lane; h < Hc; h += 64)
      lastv[h] = loadf(ctx, ((size_t)b * Lc + lidx) * Hc + h, isb) * mk;
    return;
  }
  int g = cb * 256 + t;   // 0..25599, need 8192 + 12800 + 4480 = 25472
  if (g == 0) ws[OFF_FLAG] = (float)isb;
  if (g < n0) {
    ws[OFF_MASKPF + g] = loadf(mp, g, isb);
  } else if (g < 2 * n0) {
    ws[OFF_MASKHF + (g - n0)] = loadf(mh, g - n0, isb);
  } else if (g < 2 * n0 + 64 * Hc) {
    // wT table, layout [c][h]: per-channel squared weight rows (c>=60 -> 1.0)
    int r = g - 2 * n0;
    int c = r / Hc, h = r % Hc;
    float w = 1.0f;
    if (c < 20) w = loadf(wf, (size_t)c * Hc + h, isb);
    else if (c < 40) w = loadf(watt, (size_t)(c - 20) * Hc + h, isb);
    else if (c < 60) w = loadf(wma, (size_t)(c - 40) * Hc + h, isb);
    ws[OFF_WT + r] = w * w;
  } else if (g < 2 * n0 + 64 * Hc + NPc * KP) {
    int r = g - (2 * n0 + 64 * Hc);
    int np_ = r / KP, k = r % KP;
    float w = (k < Hc) ? loadf(wmp, (size_t)np_ * Hc + k, isb) : 0.f;
    ws[OFF_W2K + r] = w * w;
  }
}

// ---------------- maxpool + cos: 64x64x224 bf16-MFMA, no LDS, frag-direct ----
// blockIdx.y in [0,NPc) -> maxpool perspective; == NPc -> cos mode (exact).
__global__ __launch_bounds__(64, 3) void maxpool_kernel(float* __restrict__ ws) {
  int s = blockIdx.x;            // 0..3
  int np_ = blockIdx.y, b = blockIdx.z;
  int pi = s >> 1, qi = s & 1;
  int cosmode = (np_ == NPc);
  int lane = threadIdx.x;        // 64, single wave
  int rsel = lane & 15, quad = lane >> 4;

  const short* Ab = (const short*)(ws + OFF_CPB)
                  + ((size_t)b * Lc + pi * 64 + rsel) * KP + quad * 8;
  const short* Bb = (const short*)(ws + OFF_CHB)
                  + ((size_t)b * Lc + qi * 64 + rsel) * KP + quad * 8;
  const float* w2k = ws + OFF_W2K + (size_t)(cosmode ? 0 : np_) * KP + quad * 8;

  float4v acc[4][4];
  float4v zf = {0.f, 0.f, 0.f, 0.f};
#pragma unroll
  for (int i = 0; i < 4; i++)
#pragma unroll
    for (int j = 0; j < 4; j++) acc[i][j] = zf;

#pragma unroll
  for (int st = 0; st < 7; st++) {
    int k0 = st * 32;
    short8v bf4[4], af[4];
#pragma unroll
    for (int t = 0; t < 4; t++)
      bf4[t] = *(const short8v*)(Bb + (size_t)t * 16 * KP + k0);
    if (cosmode) {
#pragma unroll
      for (int t = 0; t < 4; t++)
        af[t] = *(const short8v*)(Ab + (size_t)t * 16 * KP + k0);
    } else {
      float4v w0 = *(const float4v*)(w2k + k0);
      float4v w1 = *(const float4v*)(w2k + k0 + 4);
#pragma unroll
      for (int t = 0; t < 4; t++) {
        short8v ar = *(const short8v*)(Ab + (size_t)t * 16 * KP + k0);
        af[t] = weight8(ar, w0, w1);
      }
    }
#pragma unroll
    for (int i = 0; i < 4; i++)
#pragma unroll
      for (int j = 0; j < 4; j++)
        acc[i][j] = __builtin_amdgcn_mfma_f32_16x16x32_bf16(af[i], bf4[j], acc[i][j], 0, 0, 0);
  }

  if (cosmode) {
    const float* npn = ws + OFF_NORMP + b * Lc + pi * 64;
    const float* nhn = ws + OFF_NORMH + b * Lc + qi * 64;
    float nh4[4];
#pragma unroll
    for (int tj = 0; tj < 4; tj++) nh4[tj] = nhn[tj * 16 + rsel];
    float* cosp = ws + OFF_COS + (size_t)b * Lc * Lc;
    float* cost = ws + OFF_COST + (size_t)b * Lc * Lc;
#pragma unroll
    for (int ti = 0; ti < 4; ti++) {
#pragma unroll
      for (int r = 0; r < 4; r++) {
        int prow = pi * 64 + ti * 16 + quad * 4 + r;
        float npv = npn[ti * 16 + quad * 4 + r];
#pragma unroll
        for (int tj = 0; tj < 4; tj++) {
          int qcol = qi * 64 + tj * 16 + rsel;
          float v = acc[ti][tj][r] * __builtin_amdgcn_rcpf(fmaxf(npv * nh4[tj], EPSF));
          cosp[(size_t)prow * Lc + qcol] = v;
          cost[(size_t)qcol * Lc + prow] = v;
        }
      }
    }
    return;
  }

  // maxpool epilogue: v = acc / max(nwp*nwh, eps); masked max/mean partials
  const float* nwp = ws + OFF_NWP + ((size_t)b * NPc + np_) * Lc + pi * 64;
  const float* nwh = ws + OFF_NWH + ((size_t)b * NPc + np_) * Lc + qi * 64;
  const float* maskP = ws + OFF_MASKPF + b * Lc + pi * 64;
  const float* maskH = ws + OFF_MASKHF + b * Lc + qi * 64;
  float nhv[4], mhv[4], cmax[4], csum[4];
#pragma unroll
  for (int tj = 0; tj < 4; tj++) {
    int q = tj * 16 + rsel;
    nhv[tj] = nwh[q];
    mhv[tj] = maskH[q];
    cmax[tj] = NEGF;
    csum[tj] = 0.f;
  }
  size_t rbase = (((size_t)qi * Bc + b) * NPc + np_) * Lc + pi * 64;
  size_t cbase = (((size_t)pi * Bc + b) * NPc + np_) * Lc + qi * 64;
#pragma unroll
  for (int ti = 0; ti < 4; ti++) {
#pragma unroll
    for (int r = 0; r < 4; r++) {
      int p = ti * 16 + quad * 4 + r;
      float npv = nwp[p], mpv = maskP[p];
      float rm = NEGF, rs = 0.f;
#pragma unroll
      for (int tj = 0; tj < 4; tj++) {
        float v = acc[ti][tj][r] * __builtin_amdgcn_rcpf(fmaxf(npv * nhv[tj], EPSF));
        if (mhv[tj] > 0.f) rm = fmaxf(rm, v);
        rs += v * mhv[tj];
        if (mpv > 0.f) cmax[tj] = fmaxf(cmax[tj], v);
        csum[tj] += v * mpv;
      }
#pragma unroll
      for (int o = 1; o <= 8; o <<= 1) {
        rm = fmaxf(rm, __shfl_xor(rm, o));
        rs += __shfl_xor(rs, o);
      }
      if (rsel == 0) {
        ws[OFF_RPMAX + rbase + p] = rm;
        ws[OFF_RPSUM + rbase + p] = rs;
      }
    }
  }
#pragma unroll
  for (int tj = 0; tj < 4; tj++) {
#pragma unroll
    for (int o = 16; o <= 32; o <<= 1) {
      cmax[tj] = fmaxf(cmax[tj], __shfl_xor(cmax[tj], o));
      csum[tj] += __shfl_xor(csum[tj], o);
    }
  }
  if (quad == 0) {
#pragma unroll
    for (int tj = 0; tj < 4; tj++) {
      int q = tj * 16 + rsel;
      ws[OFF_CPMAX + cbase + q] = cmax[tj];
      ws[OFF_CPSUM + cbase + q] = csum[tj];
    }
  }
}

// ---------------- attmpm: att (amean/amax in LDS) + all output channels ------
// grid (Lc/4, Bc, 2); 256 threads = 4 waves; wave wv owns row r0+wv.
__global__ __launch_bounds__(256) void attmpm_kernel(float* __restrict__ ws,
                                                     void* __restrict__ out) {
  int side = blockIdx.z;
  int b = blockIdx.y;
  int r0 = blockIdx.x * 4;
  int t = threadIdx.x;  // 256
  int isb = ws[OFF_FLAG] > 0.5f;
  const float* cosrows = ws + (side ? OFF_COST : OFF_COS) + ((size_t)b * Lc + r0) * Lc;
  const float* vsrc = ws + (side ? OFF_CPM : OFF_CHM) + (size_t)b * Lc * Hc;   // other side
  const float* v1g = ws + (side ? OFF_CHM : OFF_CPM) + ((size_t)b * Lc + r0) * Hc; // own rows
  const float* vlast = ws + (side ? OFF_LASTP : OFF_LASTH) + (size_t)b * Hc;
  const float* maskLoop = ws + (side ? OFF_MASKPF : OFF_MASKHF) + b * Lc;
  const float* maskRow = ws + (side ? OFF_MASKHF : OFF_MASKPF) + b * Lc;
  float lenOther = ws[(side ? OFF_LENP : OFF_LENH) + b];
  size_t obase = (size_t)side * Bc * Lc * NCHc + ((size_t)b * Lc + r0) * NCHc;

  __shared__ float crow[4][Lc];
  __shared__ float mneg[Lc];
  __shared__ float dens[4];
  __shared__ float v1s[4][Hc];
  __shared__ float v2l[Hc];
  __shared__ float am[4][Hc];
  __shared__ float ax[4][Hc];
  for (int i = t; i < 4 * Lc; i += 256) crow[i >> 7][i & 127] = cosrows[i];
  if (t < Lc) mneg[t] = (maskLoop[t] > 0.f) ? 0.f : -1e30f;
  for (int i = t; i < 4 * Hc; i += 256) v1s[i / Hc][i % Hc] = v1g[i];
  for (int h = t; h < Hc; h += 256) v2l[h] = vlast[h];
  __syncthreads();

  // per-row stats: wave wv handles row r0+wv -> denom + out channels 0,1
  int wv = t >> 6, lane = t & 63;
  {
    float x1 = crow[wv][lane], x2 = crow[wv][lane + 64];
    float sv = x1 + x2;
    float mv = fmaxf(x1 + mneg[lane], x2 + mneg[lane + 64]);
    for (int o = 32; o > 0; o >>= 1) {
      sv += __shfl_xor(sv, o);
      mv = fmaxf(mv, __shfl_xor(mv, o));
    }
    if (lane == 0) {
      dens[wv] = sv;
      float mr = maskRow[r0 + wv];
      storef(out, obase + (size_t)wv * NCHc + 0, mr * mv, isb);
      storef(out, obase + (size_t)wv * NCHc + 1, mr * sv / fmaxf(mr * lenOther, EPSF), isb);
    }
  }
  __syncthreads();

  // attentive mean+max for the 4 rows -> LDS am/ax
  if (t < Hc) {
    float s0 = 0.f, s1 = 0.f, s2 = 0.f, s3 = 0.f;
    float m0 = NEGF, m1 = NEGF, m2 = NEGF, m3 = NEGF;
    const float* vb = vsrc + t;
#pragma unroll 4
    for (int q = 0; q < Lc; q++) {
      float pr = vb[(size_t)q * Hc];
      float mn = mneg[q];
      float v0 = crow[0][q] * pr; s0 += v0; m0 = fmaxf(m0, v0 + mn);
      float v1 = crow[1][q] * pr; s1 += v1; m1 = fmaxf(m1, v1 + mn);
      float v2 = crow[2][q] * pr; s2 += v2; m2 = fmaxf(m2, v2 + mn);
      float v3 = crow[3][q] * pr; s3 += v3; m3 = fmaxf(m3, v3 + mn);
    }
    am[0][t] = s0 / fmaxf(dens[0], EPSF);
    am[1][t] = s1 / fmaxf(dens[1], EPSF);
    am[2][t] = s2 / fmaxf(dens[2], EPSF);
    am[3][t] = s3 / fmaxf(dens[3], EPSF);
    ax[0][t] = maskRow[r0 + 0] * m0;
    ax[1][t] = maskRow[r0 + 1] * m1;
    ax[2][t] = maskRow[r0 + 2] * m2;
    ax[3][t] = maskRow[r0 + 3] * m3;
  }
  __syncthreads();

  // mpm channels: wave wv = row r0+wv, lane = channel
  int c = lane;
  int row = r0 + wv;
  size_t orow = obase + (size_t)wv * NCHc;

  // fused maxpool finalize: lanes 0..19 -> ch 23+c (max), 43+c (mean)
  if (c < NPc) {
    size_t PMX = side ? OFF_CPMAX : OFF_RPMAX;
    size_t PSM = side ? OFF_CPSUM : OFF_RPSUM;
    size_t i0 = (((size_t)0 * Bc + b) * NPc + c) * Lc + row;
    size_t i1 = (((size_t)1 * Bc + b) * NPc + c) * Lc + row;
    float m = fmaxf(ws[PMX + i0], ws[PMX + i1]);
    float sum = ws[PSM + i0] + ws[PSM + i1];
    float mk = maskRow[row];
    storef(out, orow + 23 + c, mk * m, isb);
    storef(out, orow + 43 + c, mk * sum / fmaxf(mk * lenOther, EPSF), isb);
  }

  int v2i = (c < 20) ? 0 : (c < 40) ? 1 : (c < 60) ? 2 : (c - 60);
  if (v2i > 2) v2i = 2;
  const float* y = (v2i == 0) ? v2l : (v2i == 1) ? am[wv] : ax[wv];
  const float* x = v1s[wv];
  const float* wt = ws + OFF_WT + (size_t)c * Hc;   // per-channel row, [c][h]
  float sd = 0.f, sa = 0.f, sb = 0.f;
#pragma unroll 2
  for (int h4 = 0; h4 < Hc / 4; h4++) {
    float4 wq = *(const float4*)(wt + h4 * 4);
    float4 xv = *(const float4*)&x[h4 * 4];
    float4 yv = *(const float4*)&y[h4 * 4];
    float t0;
    t0 = wq.x * xv.x; sd += t0 * yv.x; sa += t0 * xv.x; sb += wq.x * yv.x * yv.x;
    t0 = wq.y * xv.y; sd += t0 * yv.y; sa += t0 * xv.y; sb += wq.y * yv.y * yv.y;
    t0 = wq.z * xv.z; sd += t0 * yv.z; sa += t0 * xv.z; sb += wq.z * yv.z * yv.z;
    t0 = wq.w * xv.w; sd += t0 * yv.w; sa += t0 * xv.w; sb += wq.w * yv.w * yv.w;
  }
  float mm = sd / fmaxf(sqrtf(sa) * sqrtf(sb), EPSF);
  int ch;
  if (c < 20) ch = 3 + c;
  else if (c < 40) ch = 64 + (c - 20);
  else if (c < 60) ch = 85 + (c - 40);
  else if (c == 60) ch = 2;
  else if (c == 61) ch = 63;
  else if (c == 62) ch = 84;
  else ch = -1;
  if (ch >= 0) storef(out, orow + ch, mm, isb);
}

extern "C" void kernel_launch(void* const* d_in, const int* in_sizes, int n_in,
                              void* d_out, int out_size, void* d_ws, size_t ws_size,
                              hipStream_t stream) {
  const void* ctx_p = d_in[0];
  const void* mask_p = d_in[1];
  const void* ctx_h = d_in[2];
  const void* mask_h = d_in[3];
  const void* w_full = d_in[4];
  const void* w_mp = d_in[5];
  const void* w_att = d_in[6];
  const void* w_maxatt = d_in[7];
  float* ws = (float*)d_ws;

  prep_kernel<<<2164, 256, 0, stream>>>(ctx_p, mask_p, ctx_h, mask_h,
                                        w_full, w_mp, w_att, w_maxatt, ws);
  maxpool_kernel<<<dim3(4, NPc + 1, Bc), 64, 0, stream>>>(ws);
  attmpm_kernel<<<dim3(Lc / 4, Bc, 2), 256, 0, stream>>>(ws, d_out);
}

// Round 9
// 160.365 us; speedup vs baseline: 1.8675x; 1.0443x over previous
//
#include <hip/hip_runtime.h>
#include <hip/hip_bf16.h>

// BiMPM matching, B=32, L=128, H=200, NP=20.
// Input/output dtype (bf16 vs f32) detected at runtime from mask_p[0] bit
// pattern. All compute in f32 via ws. Both the maxpool GEMM and the cos GEMM
// run on bf16 MFMA with fragments loaded directly from global (no LDS);
// cos is exact (masked bf16 inputs are exactly representable), maxpool has
// one w^2*x bf16 round (|dcos| <= 2^-9). 3 launches:
// prep(+convert+lastlen), maxpool(+cos), attmpm (att + all output channels).
// attmpm inner loop is len-bounded (cos is exactly 0 at q>=len) with
// float4-packed crow (1 ds_read_b128 broadcast per q).
// Output: mv_p (32,128,105), mv_h same.

#define EPSF 1e-8f
#define NEGF -1e7f

constexpr int Bc = 32, Lc = 128, Hc = 200, NPc = 20, NCHc = 105;
constexpr int KP = 224;    // padded K (7 x 32)
constexpr size_t SLH = (size_t)Bc * Lc * Hc;   // 819200
constexpr size_t SLL = (size_t)Bc * Lc * Lc;   // 524288

// workspace layout (floats)
constexpr size_t OFF_CPM    = 0;
constexpr size_t OFF_CHM    = OFF_CPM + SLH;
constexpr size_t OFF_COS    = OFF_CHM + SLH;       // [b][p][q]
constexpr size_t OFF_COST   = OFF_COS + SLL;       // [b][q][p]
constexpr size_t OFF_NORMP  = OFF_COST + SLL;
constexpr size_t OFF_NORMH  = OFF_NORMP + (size_t)Bc * Lc;
constexpr size_t OFF_LENP   = OFF_NORMH + (size_t)Bc * Lc;
constexpr size_t OFF_LENH   = OFF_LENP + Bc;
constexpr size_t OFF_LASTP  = OFF_LENH + Bc;
constexpr size_t OFF_LASTH  = OFF_LASTP + (size_t)Bc * Hc;
constexpr size_t OFF_NWP    = OFF_LASTH + (size_t)Bc * Hc;  // [b][np][l]
constexpr size_t OFF_NWH    = OFF_NWP + (size_t)Bc * NPc * Lc;
constexpr size_t OFF_MASKPF = OFF_NWH + (size_t)Bc * NPc * Lc;
constexpr size_t OFF_MASKHF = OFF_MASKPF + (size_t)Bc * Lc;
constexpr size_t OFF_FLAG   = OFF_MASKHF + (size_t)Bc * Lc;
constexpr size_t OFF_WT     = OFF_FLAG + 64;                // [c][h] squared weights, 64 x Hc
constexpr size_t OFF_RPMAX  = OFF_WT + (size_t)Hc * 64;     // [qi][b][np][p]
constexpr size_t OFF_RPSUM  = OFF_RPMAX + 2 * (size_t)Bc * NPc * Lc;
constexpr size_t OFF_CPMAX  = OFF_RPSUM + 2 * (size_t)Bc * NPc * Lc;  // [pi][b][np][q]
constexpr size_t OFF_CPSUM  = OFF_CPMAX + 2 * (size_t)Bc * NPc * Lc;
constexpr size_t OFF_CHB    = OFF_CPSUM + 2 * (size_t)Bc * NPc * Lc;  // bf16 [b][l][KP]
constexpr size_t OFF_CPB    = OFF_CHB + ((size_t)Bc * Lc * KP) / 2;   // bf16 [b][l][KP]
constexpr size_t OFF_W2K    = OFF_CPB + ((size_t)Bc * Lc * KP) / 2;   // f32 [np][KP]
constexpr size_t WS_FLOATS  = OFF_W2K + (size_t)NPc * KP;

typedef __attribute__((ext_vector_type(8))) short short8v;
typedef __attribute__((ext_vector_type(4))) float float4v;

__device__ __forceinline__ float loadf(const void* p, size_t i, int isb) {
  if (isb) return __bfloat162float(((const __hip_bfloat16*)p)[i]);
  return ((const float*)p)[i];
}

__device__ __forceinline__ void storef(void* out, size_t i, float v, int isb) {
  if (isb) ((__hip_bfloat16*)out)[i] = __float2bfloat16(v);
  else ((float*)out)[i] = v;
}

__device__ __forceinline__ short b2s(float f) {
  __hip_bfloat16 h = __float2bfloat16(f);
  union { __hip_bfloat16 b; short s; } u;
  u.b = h;
  return u.s;
}

// unpack bf16 lane, scale by w (f32), repack to bf16
__device__ __forceinline__ short8v weight8(short8v a, float4v w0, float4v w1) {
  short8v r;
#pragma unroll
  for (int e = 0; e < 8; e++) {
    union { unsigned u; float f; } c;
    c.u = ((unsigned)(unsigned short)a[e]) << 16;
    float w = (e < 4) ? w0[e] : w1[e - 4];
    r[e] = b2s(c.f * w);
  }
  return r;
}

// ---------------- prep (+convert +lastlen), one launch -----------------------
__global__ __launch_bounds__(256) void prep_kernel(
    const void* __restrict__ cp_, const void* __restrict__ mp,
    const void* __restrict__ ch_, const void* __restrict__ mh,
    const void* __restrict__ wf, const void* __restrict__ wmp,
    const void* __restrict__ watt, const void* __restrict__ wma,
    float* __restrict__ ws) {
  int isb = (((const unsigned short*)mp)[0] == 0x3F80u) ? 1 : 0;
  int bid = blockIdx.x;
  int t = threadIdx.x;
  const int n0 = Bc * Lc;          // 4096
  if (bid < 2048) {
    int g = bid * 4 + (t >> 6);    // row index 0..8191
    int side = g >> 12;
    int bl = g & 4095;
    int b = bl >> 7, l = bl & 127;
    int lane = t & 63;
    const void* ctx = side ? ch_ : cp_;
    const void* maskin = side ? mh : mp;
    float mk = loadf(maskin, b * Lc + l, isb);
    size_t rowbase = ((size_t)b * Lc + l) * Hc;
    float* cm = ws + (side ? OFF_CHM : OFF_CPM) + rowbase;
    __hip_bfloat16* cb16 = (__hip_bfloat16*)(ws + (side ? OFF_CHB : OFF_CPB));
    size_t cb = ((size_t)b * Lc + l) * KP;

    float v[4];
    float ss = 0.f;
    for (int i = 0; i < 4; i++) {
      int h = lane + 64 * i;
      float x = 0.f;
      if (h < Hc) {
        x = loadf(ctx, rowbase + h, isb) * mk;
        cm[h] = x;
        cb16[cb + h] = __float2bfloat16(x);
      } else if (h < KP) {
        cb16[cb + h] = __float2bfloat16(0.f);
      }
      v[i] = x;
      ss += x * x;
    }
    for (int o = 32; o > 0; o >>= 1) ss += __shfl_xor(ss, o);
    if (lane == 0) ws[(side ? OFF_NORMH : OFF_NORMP) + b * Lc + l] = sqrtf(ss);

    float* nw = ws + (side ? OFF_NWH : OFF_NWP) + (size_t)b * NPc * Lc;
    for (int np_ = 0; np_ < NPc; np_++) {
      float s = 0.f;
      for (int i = 0; i < 4; i++) {
        int h = lane + 64 * i;
        if (h < Hc) {
          float w = loadf(wmp, (size_t)np_ * Hc + h, isb);
          float wx = w * v[i];
          s += wx * wx;
        }
      }
      for (int o = 32; o > 0; o >>= 1) s += __shfl_xor(s, o);
      if (lane == 0) nw[np_ * Lc + l] = sqrtf(s);
    }
    return;
  }
  int cb = bid - 2048;
  if (cb >= 100) {
    // lastlen: 16 blocks x 4 (side,b) pairs, one wave per pair
    int idx = (cb - 100) * 4 + (t >> 6);   // 0..63
    int side = idx >> 5, b = idx & 31;
    int lane = t & 63;
    const void* mask = side ? mh : mp;
    const void* ctx = side ? ch_ : cp_;
    float s = 0.f;
    for (int l = lane; l < Lc; l += 64) s += loadf(mask, b * Lc + l, isb);
    for (int o = 32; o > 0; o >>= 1) s += __shfl_xor(s, o);
    if (lane == 0) ws[(side ? OFF_LENH : OFF_LENP) + b] = s;
    int lidx = (int)(s + 0.5f) - 1;
    if (lidx < 0) lidx = 0;
    float mk = loadf(mask, b * Lc + lidx, isb);
    float* lastv = ws + (side ? OFF_LASTH : OFF_LASTP) + (size_t)b * Hc;
    for (int h = lane; h < Hc; h += 64)
      lastv[h] = loadf(ctx, ((size_t)b * Lc + lidx) * Hc + h, isb) * mk;
    return;
  }
  int g = cb * 256 + t;
  if (g == 0) ws[OFF_FLAG] = (float)isb;
  if (g < n0) {
    ws[OFF_MASKPF + g] = loadf(mp, g, isb);
  } else if (g < 2 * n0) {
    ws[OFF_MASKHF + (g - n0)] = loadf(mh, g - n0, isb);
  } else if (g < 2 * n0 + 64 * Hc) {
    // wT table, layout [c][h]: per-channel squared weight rows (c>=60 -> 1.0)
    int r = g - 2 * n0;
    int c = r / Hc, h = r % Hc;
    float w = 1.0f;
    if (c < 20) w = loadf(wf, (size_t)c * Hc + h, isb);
    else if (c < 40) w = loadf(watt, (size_t)(c - 20) * Hc + h, isb);
    else if (c < 60) w = loadf(wma, (size_t)(c - 40) * Hc + h, isb);
    ws[OFF_WT + r] = w * w;
  } else if (g < 2 * n0 + 64 * Hc + NPc * KP) {
    int r = g - (2 * n0 + 64 * Hc);
    int np_ = r / KP, k = r % KP;
    float w = (k < Hc) ? loadf(wmp, (size_t)np_ * Hc + k, isb) : 0.f;
    ws[OFF_W2K + r] = w * w;
  }
}

// ---------------- maxpool + cos: 64x64x224 bf16-MFMA, no LDS, frag-direct ----
// blockIdx.y in [0,NPc) -> maxpool perspective; == NPc -> cos mode (exact).
__global__ __launch_bounds__(64, 3) void maxpool_kernel(float* __restrict__ ws) {
  int s = blockIdx.x;            // 0..3
  int np_ = blockIdx.y, b = blockIdx.z;
  int pi = s >> 1, qi = s & 1;
  int cosmode = (np_ == NPc);
  int lane = threadIdx.x;        // 64, single wave
  int rsel = lane & 15, quad = lane >> 4;

  const short* Ab = (const short*)(ws + OFF_CPB)
                  + ((size_t)b * Lc + pi * 64 + rsel) * KP + quad * 8;
  const short* Bb = (const short*)(ws + OFF_CHB)
                  + ((size_t)b * Lc + qi * 64 + rsel) * KP + quad * 8;
  const float* w2k = ws + OFF_W2K + (size_t)(cosmode ? 0 : np_) * KP + quad * 8;

  float4v acc[4][4];
  float4v zf = {0.f, 0.f, 0.f, 0.f};
#pragma unroll
  for (int i = 0; i < 4; i++)
#pragma unroll
    for (int j = 0; j < 4; j++) acc[i][j] = zf;

#pragma unroll
  for (int st = 0; st < 7; st++) {
    int k0 = st * 32;
    short8v bf4[4], af[4];
#pragma unroll
    for (int t = 0; t < 4; t++)
      bf4[t] = *(const short8v*)(Bb + (size_t)t * 16 * KP + k0);
    if (cosmode) {
#pragma unroll
      for (int t = 0; t < 4; t++)
        af[t] = *(const short8v*)(Ab + (size_t)t * 16 * KP + k0);
    } else {
      float4v w0 = *(const float4v*)(w2k + k0);
      float4v w1 = *(const float4v*)(w2k + k0 + 4);
#pragma unroll
      for (int t = 0; t < 4; t++) {
        short8v ar = *(const short8v*)(Ab + (size_t)t * 16 * KP + k0);
        af[t] = weight8(ar, w0, w1);
      }
    }
#pragma unroll
    for (int i = 0; i < 4; i++)
#pragma unroll
      for (int j = 0; j < 4; j++)
        acc[i][j] = __builtin_amdgcn_mfma_f32_16x16x32_bf16(af[i], bf4[j], acc[i][j], 0, 0, 0);
  }

  if (cosmode) {
    const float* npn = ws + OFF_NORMP + b * Lc + pi * 64;
    const float* nhn = ws + OFF_NORMH + b * Lc + qi * 64;
    float nh4[4];
#pragma unroll
    for (int tj = 0; tj < 4; tj++) nh4[tj] = nhn[tj * 16 + rsel];
    float* cosp = ws + OFF_COS + (size_t)b * Lc * Lc;
    float* cost = ws + OFF_COST + (size_t)b * Lc * Lc;
#pragma unroll
    for (int ti = 0; ti < 4; ti++) {
#pragma unroll
      for (int r = 0; r < 4; r++) {
        int prow = pi * 64 + ti * 16 + quad * 4 + r;
        float npv = npn[ti * 16 + quad * 4 + r];
#pragma unroll
        for (int tj = 0; tj < 4; tj++) {
          int qcol = qi * 64 + tj * 16 + rsel;
          float v = acc[ti][tj][r] * __builtin_amdgcn_rcpf(fmaxf(npv * nh4[tj], EPSF));
          cosp[(size_t)prow * Lc + qcol] = v;
          cost[(size_t)qcol * Lc + prow] = v;
        }
      }
    }
    return;
  }

  // maxpool epilogue: v = acc / max(nwp*nwh, eps); masked max/mean partials
  const float* nwp = ws + OFF_NWP + ((size_t)b * NPc + np_) * Lc + pi * 64;
  const float* nwh = ws + OFF_NWH + ((size_t)b * NPc + np_) * Lc + qi * 64;
  const float* maskP = ws + OFF_MASKPF + b * Lc + pi * 64;
  const float* maskH = ws + OFF_MASKHF + b * Lc + qi * 64;
  float nhv[4], mhv[4], cmax[4], csum[4];
#pragma unroll
  for (int tj = 0; tj < 4; tj++) {
    int q = tj * 16 + rsel;
    nhv[tj] = nwh[q];
    mhv[tj] = maskH[q];
    cmax[tj] = NEGF;
    csum[tj] = 0.f;
  }
  size_t rbase = (((size_t)qi * Bc + b) * NPc + np_) * Lc + pi * 64;
  size_t cbase = (((size_t)pi * Bc + b) * NPc + np_) * Lc + qi * 64;
#pragma unroll
  for (int ti = 0; ti < 4; ti++) {
#pragma unroll
    for (int r = 0; r < 4; r++) {
      int p = ti * 16 + quad * 4 + r;
      float npv = nwp[p], mpv = maskP[p];
      float rm = NEGF, rs = 0.f;
#pragma unroll
      for (int tj = 0; tj < 4; tj++) {
        float v = acc[ti][tj][r] * __builtin_amdgcn_rcpf(fmaxf(npv * nhv[tj], EPSF));
        if (mhv[tj] > 0.f) rm = fmaxf(rm, v);
        rs += v * mhv[tj];
        if (mpv > 0.f) cmax[tj] = fmaxf(cmax[tj], v);
        csum[tj] += v * mpv;
      }
#pragma unroll
      for (int o = 1; o <= 8; o <<= 1) {
        rm = fmaxf(rm, __shfl_xor(rm, o));
        rs += __shfl_xor(rs, o);
      }
      if (rsel == 0) {
        ws[OFF_RPMAX + rbase + p] = rm;
        ws[OFF_RPSUM + rbase + p] = rs;
      }
    }
  }
#pragma unroll
  for (int tj = 0; tj < 4; tj++) {
#pragma unroll
    for (int o = 16; o <= 32; o <<= 1) {
      cmax[tj] = fmaxf(cmax[tj], __shfl_xor(cmax[tj], o));
      csum[tj] += __shfl_xor(csum[tj], o);
    }
  }
  if (quad == 0) {
#pragma unroll
    for (int tj = 0; tj < 4; tj++) {
      int q = tj * 16 + rsel;
      ws[OFF_CPMAX + cbase + q] = cmax[tj];
      ws[OFF_CPSUM + cbase + q] = csum[tj];
    }
  }
}

// ---------------- attmpm: att (len-bounded, f4 crow) + all output channels ---
// grid (Lc/4, Bc, 2); 256 threads = 4 waves; wave wv owns row r0+wv.
__global__ __launch_bounds__(256) void attmpm_kernel(float* __restrict__ ws,
                                                     void* __restrict__ out) {
  int side = blockIdx.z;
  int b = blockIdx.y;
  int r0 = blockIdx.x * 4;
  int t = threadIdx.x;  // 256
  int isb = ws[OFF_FLAG] > 0.5f;
  const float* cosrows = ws + (side ? OFF_COST : OFF_COS) + ((size_t)b * Lc + r0) * Lc;
  const float* vsrc = ws + (side ? OFF_CPM : OFF_CHM) + (size_t)b * Lc * Hc;   // other side
  const float* v1g = ws + (side ? OFF_CHM : OFF_CPM) + ((size_t)b * Lc + r0) * Hc; // own rows
  const float* vlast = ws + (side ? OFF_LASTP : OFF_LASTH) + (size_t)b * Hc;
  const float* maskRow = ws + (side ? OFF_MASKHF : OFF_MASKPF) + b * Lc;
  float lenOther = ws[(side ? OFF_LENP : OFF_LENH) + b];
  int lenO = (int)(lenOther + 0.5f);   // valid q = [0, lenO); cos==0 beyond
  size_t obase = (size_t)side * Bc * Lc * NCHc + ((size_t)b * Lc + r0) * NCHc;

  __shared__ float crowT[Lc][4];   // [q][row] packed for one b128 per q
  __shared__ float dens[4];
  __shared__ float v1s[4][Hc];
  __shared__ float v2l[Hc];
  __shared__ float am[4][Hc];
  __shared__ float ax[4][Hc];
  for (int i = t; i < 4 * Lc; i += 256) {
    int row = i >> 7, q = i & 127;
    crowT[q][row] = cosrows[(size_t)row * Lc + q];
  }
  for (int i = t; i < 4 * Hc; i += 256) v1s[i / Hc][i % Hc] = v1g[i];
  for (int h = t; h < Hc; h += 256) v2l[h] = vlast[h];
  __syncthreads();

  // per-row stats: wave wv handles row r0+wv -> denom + out channels 0,1
  int wv = t >> 6, lane = t & 63;
  {
    float x1 = crowT[lane][wv], x2 = crowT[lane + 64][wv];
    float sv = x1 + x2;               // x2 is exactly 0 beyond len
    float mv = fmaxf(x1, (lane + 64 < lenO) ? x2 : NEGF);  // len>=64: x1 always valid
    for (int o = 32; o > 0; o >>= 1) {
      sv += __shfl_xor(sv, o);
      mv = fmaxf(mv, __shfl_xor(mv, o));
    }
    if (lane == 0) {
      dens[wv] = sv;
      float mr = maskRow[r0 + wv];
      storef(out, obase + (size_t)wv * NCHc + 0, mr * mv, isb);
      storef(out, obase + (size_t)wv * NCHc + 1, mr * sv / fmaxf(mr * lenOther, EPSF), isb);
    }
  }
  __syncthreads();

  // attentive mean+max for the 4 rows -> LDS am/ax (loop only over valid q)
  if (t < Hc) {
    float s0 = 0.f, s1 = 0.f, s2 = 0.f, s3 = 0.f;
    float m0 = NEGF, m1 = NEGF, m2 = NEGF, m3 = NEGF;
    const float* vb = vsrc + t;
#pragma unroll 4
    for (int q = 0; q < lenO; q++) {
      float pr = vb[(size_t)q * Hc];
      float4 c4 = *(const float4*)&crowT[q][0];
      float v0 = c4.x * pr; s0 += v0; m0 = fmaxf(m0, v0);
      float v1 = c4.y * pr; s1 += v1; m1 = fmaxf(m1, v1);
      float v2 = c4.z * pr; s2 += v2; m2 = fmaxf(m2, v2);
      float v3 = c4.w * pr; s3 += v3; m3 = fmaxf(m3, v3);
    }
    am[0][t] = s0 / fmaxf(dens[0], EPSF);
    am[1][t] = s1 / fmaxf(dens[1], EPSF);
    am[2][t] = s2 / fmaxf(dens[2], EPSF);
    am[3][t] = s3 / fmaxf(dens[3], EPSF);
    ax[0][t] = maskRow[r0 + 0] * m0;
    ax[1][t] = maskRow[r0 + 1] * m1;
    ax[2][t] = maskRow[r0 + 2] * m2;
    ax[3][t] = maskRow[r0 + 3] * m3;
  }
  __syncthreads();

  // mpm channels: wave wv = row r0+wv, lane = channel
  int c = lane;
  int row = r0 + wv;
  size_t orow = obase + (size_t)wv * NCHc;

  // fused maxpool finalize: lanes 0..19 -> ch 23+c (max), 43+c (mean)
  if (c < NPc) {
    size_t PMX = side ? OFF_CPMAX : OFF_RPMAX;
    size_t PSM = side ? OFF_CPSUM : OFF_RPSUM;
    size_t i0 = (((size_t)0 * Bc + b) * NPc + c) * Lc + row;
    size_t i1 = (((size_t)1 * Bc + b) * NPc + c) * Lc + row;
    float m = fmaxf(ws[PMX + i0], ws[PMX + i1]);
    float sum = ws[PSM + i0] + ws[PSM + i1];
    float mk = maskRow[row];
    storef(out, orow + 23 + c, mk * m, isb);
    storef(out, orow + 43 + c, mk * sum / fmaxf(mk * lenOther, EPSF), isb);
  }

  int v2i = (c < 20) ? 0 : (c < 40) ? 1 : (c < 60) ? 2 : (c - 60);
  if (v2i > 2) v2i = 2;
  const float* y = (v2i == 0) ? v2l : (v2i == 1) ? am[wv] : ax[wv];
  const float* x = v1s[wv];
  const float* wt = ws + OFF_WT + (size_t)c * Hc;   // per-channel row, [c][h]
  float sd = 0.f, sa = 0.f, sb = 0.f;
#pragma unroll 2
  for (int h4 = 0; h4 < Hc / 4; h4++) {
    float4 wq = *(const float4*)(wt + h4 * 4);
    float4 xv = *(const float4*)&x[h4 * 4];
    float4 yv = *(const float4*)&y[h4 * 4];
    float t0;
    t0 = wq.x * xv.x; sd += t0 * yv.x; sa += t0 * xv.x; sb += wq.x * yv.x * yv.x;
    t0 = wq.y * xv.y; sd += t0 * yv.y; sa += t0 * xv.y; sb += wq.y * yv.y * yv.y;
    t0 = wq.z * xv.z; sd += t0 * yv.z; sa += t0 * xv.z; sb += wq.z * yv.z * yv.z;
    t0 = wq.w * xv.w; sd += t0 * yv.w; sa += t0 * xv.w; sb += wq.w * yv.w * yv.w;
  }
  float mm = sd / fmaxf(sqrtf(sa) * sqrtf(sb), EPSF);
  int ch;
  if (c < 20) ch = 3 + c;
  else if (c < 40) ch = 64 + (c - 20);
  else if (c < 60) ch = 85 + (c - 40);
  else if (c == 60) ch = 2;
  else if (c == 61) ch = 63;
  else if (c == 62) ch = 84;
  else ch = -1;
  if (ch >= 0) storef(out, orow + ch, mm, isb);
}

extern "C" void kernel_launch(void* const* d_in, const int* in_sizes, int n_in,
                              void* d_out, int out_size, void* d_ws, size_t ws_size,
                              hipStream_t stream) {
  const void* ctx_p = d_in[0];
  const void* mask_p = d_in[1];
  const void* ctx_h = d_in[2];
  const void* mask_h = d_in[3];
  const void* w_full = d_in[4];
  const void* w_mp = d_in[5];
  const void* w_att = d_in[6];
  const void* w_maxatt = d_in[7];
  float* ws = (float*)d_ws;

  prep_kernel<<<2164, 256, 0, stream>>>(ctx_p, mask_p, ctx_h, mask_h,
                                        w_full, w_mp, w_att, w_maxatt, ws);
  maxpool_kernel<<<dim3(4, NPc + 1, Bc), 64, 0, stream>>>(ws);
  attmpm_kernel<<<dim3(Lc / 4, Bc, 2), 256, 0, stream>>>(ws, d_out);
}